// Round 14
// baseline (652.968 us; speedup 1.0000x reference)
//
#include <hip/hip_runtime.h>
#include <math.h>

typedef __bf16 bf16;
typedef __bf16 bf16x8 __attribute__((ext_vector_type(8)));
typedef __bf16 bf16x4 __attribute__((ext_vector_type(4)));
typedef float f32x4 __attribute__((ext_vector_type(4)));

#define MFMA_B16(a,b,c) __builtin_amdgcn_mfma_f32_16x16x32_bf16((a),(b),(c),0,0,0)

constexpr int TMAXc = 30;
constexpr int Bc = 128, Pc = 196, Fc = 2048, Ec = 512, Hc = 1024, Vc = 10000;
constexpr int G4c = 4 * Hc;          // 4096
constexpr int NSTEP = TMAXc + 1;     // 31
constexpr int MALLc = NSTEP * Bc;    // 3968
constexpr int MOUTc = TMAXc * Bc;    // 3840
constexpr int NBLK = 256;            // persistent kernel grid

__device__ __forceinline__ float fsigm(float x){
  return __fdividef(1.0f, 1.0f + __expf(-x));
}
__device__ __forceinline__ float ftanh(float x){
  return 1.0f - __fdividef(2.0f, __expf(2.0f*x) + 1.0f);
}
// 4-way select by runtime index (3 cndmask, no scratch - rule #20 safe)
__device__ __forceinline__ float sel4(float a, float b, float c, float d, int i){
  float x = (i & 1) ? b : a;
  float y = (i & 1) ? d : c;
  return (i & 2) ? y : x;
}

__device__ __forceinline__ void gll16(const void* g, void* l){
  __builtin_amdgcn_global_load_lds((const __attribute__((address_space(1))) void*)g,
                                   (__attribute__((address_space(3))) void*)l, 16, 0, 0);
}

// 16B write-through store (bypasses L1/L2, lands at coherence point / MALL)
__device__ __forceinline__ void wt16(bf16* p, bf16x8 v){
  asm volatile("global_store_dwordx4 %0, %1, off sc0 sc1" :: "v"(p), "v"(v) : "memory");
}

__device__ __forceinline__ int aldf(int* f){
  return __hip_atomic_load(f, __ATOMIC_RELAXED, __HIP_MEMORY_SCOPE_AGENT);
}

// bounded spin: escapes after ~1ms (s_memrealtime = 100 MHz const clock)
__device__ __forceinline__ void waitflag(int* f, int tgt){
  long long t0 = __builtin_amdgcn_s_memrealtime();
  while (aldf(f) < tgt) {
    __builtin_amdgcn_s_sleep(1);
    if (__builtin_amdgcn_s_memrealtime() - t0 > 100000) break;
  }
}

// poll gate0 while snapshotting gates 1-3 in the same round trip
__device__ __forceinline__ void waitflags4(int* F, int& f1, int& f2, int& f3){
  long long t0 = __builtin_amdgcn_s_memrealtime();
  for (;;) {
    int f0 = aldf(F + 0);
    f1 = aldf(F + 1);
    f2 = aldf(F + 2);
    f3 = aldf(F + 3);
    if (f0 >= 32) break;
    __builtin_amdgcn_s_sleep(1);
    if (__builtin_amdgcn_s_memrealtime() - t0 > 100000) break;
  }
}

// ---------------- prep kernels ----------------

__global__ void mean_kernel(const float* __restrict__ enc, bf16* __restrict__ feat){
  int blk = blockIdx.x, b = blk >> 1, half = blk & 1;
  int f0 = half*1024 + threadIdx.x*4;
  const float* p = enc + (size_t)b*Pc*Fc + f0;
  float4 s = {0.f,0.f,0.f,0.f};
  #pragma unroll 4
  for (int q = 0; q < Pc; ++q) {
    float4 v = *(const float4*)(p + (size_t)q*Fc);
    s.x += v.x; s.y += v.y; s.z += v.z; s.w += v.w;
  }
  const float r = 1.0f/(float)Pc;
  bf16x4 o = { (bf16)(s.x*r), (bf16)(s.y*r), (bf16)(s.z*r), (bf16)(s.w*r) };
  *(bf16x4*)&feat[b*Fc + f0] = o;
}

__global__ void conv_kernel(const float* __restrict__ src, bf16* __restrict__ dst, int n4){
  int i = blockIdx.x*256 + threadIdx.x;
  if (i >= n4) return;
  float4 v = ((const float4*)src)[i];
  bf16x4 o = { (bf16)v.x, (bf16)v.y, (bf16)v.z, (bf16)v.w };
  *(bf16x4*)&dst[i*4] = o;
}

__global__ void permconv_ih(const float* __restrict__ W, bf16* __restrict__ Wp){
  int i = blockIdx.x*256 + threadIdx.x;
  if (i >= G4c*Ec/4) return;
  int i4 = i*4;
  int rp = i4 >> 9, k = i4 & 511;
  int g = rp & 3, j = rp >> 2;
  float4 v = *(const float4*)&W[(size_t)(g*Hc + j)*Ec + k];
  bf16x4 o = { (bf16)v.x, (bf16)v.y, (bf16)v.z, (bf16)v.w };
  *(bf16x4*)&Wp[i4] = o;
}

__global__ void permsplit_hh(const float* __restrict__ W, bf16* __restrict__ Whi, bf16* __restrict__ Wlo){
  int i = blockIdx.x*256 + threadIdx.x;
  if (i >= G4c*Hc/4) return;
  int i4 = i*4;
  int rp = i4 >> 10, k = i4 & 1023;
  int g = rp & 3, j = rp >> 2;
  float4 v = *(const float4*)&W[(size_t)(g*Hc + j)*Hc + k];
  bf16 h0=(bf16)v.x, h1=(bf16)v.y, h2=(bf16)v.z, h3=(bf16)v.w;
  bf16x4 hi = { h0, h1, h2, h3 };
  bf16x4 lo = { (bf16)(v.x-(float)h0), (bf16)(v.y-(float)h1), (bf16)(v.z-(float)h2), (bf16)(v.w-(float)h3) };
  *(bf16x4*)&Whi[i4] = hi;
  *(bf16x4*)&Wlo[i4] = lo;
}

__global__ void split_kernel(const float* __restrict__ W, bf16* __restrict__ Whi, bf16* __restrict__ Wlo, int n4){
  int i = blockIdx.x*256 + threadIdx.x;
  if (i >= n4) return;
  float4 v = ((const float4*)W)[i];
  bf16 h0=(bf16)v.x, h1=(bf16)v.y, h2=(bf16)v.z, h3=(bf16)v.w;
  bf16x4 hi = { h0, h1, h2, h3 };
  bf16x4 lo = { (bf16)(v.x-(float)h0), (bf16)(v.y-(float)h1), (bf16)(v.z-(float)h2), (bf16)(v.w-(float)h3) };
  *(bf16x4*)&Whi[i*4] = hi;
  *(bf16x4*)&Wlo[i*4] = lo;
}

__global__ void bcomb_kernel(const float* __restrict__ bih, const float* __restrict__ bhh, float* __restrict__ bc){
  int i = blockIdx.x*256 + threadIdx.x;
  if (i >= G4c) return;
  int g = i & 3, j = i >> 2;
  bc[i] = bih[g*Hc + j] + bhh[g*Hc + j];
}

__global__ void gather_kernel(const float* __restrict__ emb, const int* __restrict__ gt, bf16* __restrict__ X){
  int idx = blockIdx.x*256 + threadIdx.x;
  if (idx >= MOUTc*(Ec/4)) return;
  int r = idx >> 7, ei = (idx & 127) * 4;
  int s = (r >> 7) + 1, b = r & 127;
  int tok = gt[b*(TMAXc+1) + (s-1)];
  float4 v = *(const float4*)(emb + (size_t)tok*Ec + ei);
  bf16x4 o = { (bf16)v.x, (bf16)v.y, (bf16)v.z, (bf16)v.w };
  *(bf16x4*)&X[(size_t)(s*Bc + b)*Ec + ei] = o;
}

__global__ void build_ridx(const int* __restrict__ lens, int* __restrict__ meta){
  int i = blockIdx.x*256 + threadIdx.x;
  if (i >= MOUTc) return;
  int t = i >> 7, b = i & 127;
  int S = 0, R = 0;
  for (int bb = 0; bb < 128; ++bb) {
    int l = lens[bb] - 1;
    S += (t < l) ? t : l;
    R += l;
  }
  if (i == 0) meta[0] = R;
  if (i >= R) meta[1 + i] = 0;
  if (t < lens[b] - 1) meta[1 + S + b] = i;
}

__global__ void zerofill(const int* __restrict__ lens, float* __restrict__ out){
  int i = blockIdx.x*256 + threadIdx.x;
  if (i >= MOUTc*2500) return;
  int row = i / 2500, c4 = i - row*2500;
  int b = row / TMAXc, t = row - b*TMAXc;
  if (t >= lens[b] - 1) {
    float4 z = {0.f,0.f,0.f,0.f};
    *(float4*)(out + (size_t)row*Vc + c4*4) = z;
  }
}

// ---------------- GEMM A split-K: x0 partials (32 blocks = 4 ntiles x 8 kchunks) ----------
__global__ __launch_bounds__(256, 2) void initA(
  const bf16* __restrict__ feat, const bf16* __restrict__ Wi, float* __restrict__ part)
{
  __shared__ alignas(16) bf16 sA[128*32], sB[128*32];
  int tid = threadIdx.x, lane = tid & 63, w = tid >> 6, wr = w >> 1, wc = w & 1;
  int nt = blockIdx.x & 3, kc = blockIdx.x >> 2;
  int n0 = nt*128;

  f32x4 acc[4][4] = {};
  for (int kt = kc*256; kt < kc*256 + 256; kt += 32) {
    #pragma unroll
    for (int is = 0; is < 2; ++is) {
      int p = tid*16 + is*4096;
      int r = p >> 6, c = (p & 63) >> 1;
      int ldsoff = w*512 + is*2048;
      gll16(feat + (size_t)r*Fc + kt + c, &sA[ldsoff]);
      gll16(Wi + (size_t)(n0 + r)*Fc + kt + c, &sB[ldsoff]);
    }
    __syncthreads();
    int koff = (lane >> 4) * 8;
    bf16x8 ah[4], bh[4];
    #pragma unroll
    for (int mi = 0; mi < 4; ++mi)
      ah[mi] = *(const bf16x8*)&sA[(wr*64 + mi*16 + (lane & 15))*32 + koff];
    #pragma unroll
    for (int ni = 0; ni < 4; ++ni)
      bh[ni] = *(const bf16x8*)&sB[(wc*64 + ni*16 + (lane & 15))*32 + koff];
    #pragma unroll
    for (int mi = 0; mi < 4; ++mi)
      #pragma unroll
      for (int ni = 0; ni < 4; ++ni)
        acc[mi][ni] = MFMA_B16(ah[mi], bh[ni], acc[mi][ni]);
    __syncthreads();
  }
  #pragma unroll
  for (int mi = 0; mi < 4; ++mi)
    #pragma unroll
    for (int ni = 0; ni < 4; ++ni) {
      int lrow = wr*64 + mi*16 + ((lane >> 4) << 2);
      int col = n0 + wc*64 + ni*16 + (lane & 15);
      #pragma unroll
      for (int j = 0; j < 4; ++j)
        part[((size_t)kc*128 + lrow + j)*512 + col] = acc[mi][ni][j];
    }
}

__global__ void initB(const float* __restrict__ part, const float* __restrict__ binit,
                      const float* __restrict__ gam, const float* __restrict__ bet,
                      bf16* __restrict__ Xall)
{
  int i = blockIdx.x*256 + threadIdx.x;
  if (i >= 128*512) return;
  int col = i & 511;
  float v = 0.f;
  #pragma unroll
  for (int kc = 0; kc < 8; ++kc) v += part[(size_t)kc*128*512 + i];
  const float rbn = rsqrtf(1.0f + 1e-5f);
  v = fsigm(v + binit[col]);
  v = gam[col]*(v*rbn) + bet[col];
  Xall[i] = (bf16)v;
}

// ---------------- Xg GEMM (128x128 tile, BK=32, nt-major, XCD swizzle) --------
__global__ __launch_bounds__(256, 2) void gemm_xg(
  const bf16* __restrict__ A, const bf16* __restrict__ B,
  int M, int N, int K, int mtiles,
  const float* __restrict__ p0, bf16* __restrict__ outb)
{
  constexpr int BK = 32;
  __shared__ alignas(16) bf16 sAh[128*BK], sBh[128*BK];

  int tid = threadIdx.x;
  int lane = tid & 63, w = tid >> 6, wr = w >> 1, wc = w & 1;
  int bid = blockIdx.x;
  {
    int nwg = gridDim.x, q = nwg >> 3, r = nwg & 7;
    int x = bid & 7, o = bid >> 3;
    bid = (x < r ? x*(q+1) : r*(q+1) + (x-r)*q) + o;
  }
  int nt = bid / mtiles, mt = bid - nt*mtiles;
  int m0 = mt*128, n0 = nt*128;

  int sr = (tid*16) >> 6;
  int gr0 = m0 + sr, gr1 = m0 + sr + 64;

  f32x4 acc[4][4] = {};

  for (int kt = 0; kt < K; kt += BK) {
    #pragma unroll
    for (int is = 0; is < 2; ++is) {
      int p = tid*16 + is*4096;
      int c = (p & 63) >> 1;
      int r = p >> 6;
      int ldsoff = w*512 + is*2048;
      int ga = is ? gr1 : gr0;
      gll16(A + (size_t)ga*K + kt + c, &sAh[ldsoff]);
      gll16(B + (size_t)(n0 + r)*K + kt + c, &sBh[ldsoff]);
    }
    __syncthreads();

    int koff = (lane >> 4) * 8;
    bf16x8 ah[4], bh[4];
    #pragma unroll
    for (int mi = 0; mi < 4; ++mi)
      ah[mi] = *(const bf16x8*)&sAh[(wr*64 + mi*16 + (lane & 15))*BK + koff];
    #pragma unroll
    for (int ni = 0; ni < 4; ++ni)
      bh[ni] = *(const bf16x8*)&sBh[(wc*64 + ni*16 + (lane & 15))*BK + koff];
    #pragma unroll
    for (int mi = 0; mi < 4; ++mi)
      #pragma unroll
      for (int ni = 0; ni < 4; ++ni)
        acc[mi][ni] = MFMA_B16(ah[mi], bh[ni], acc[mi][ni]);
    __syncthreads();
  }

  #pragma unroll
  for (int mi = 0; mi < 4; ++mi)
    #pragma unroll
    for (int ni = 0; ni < 4; ++ni) {
      int lrow = m0 + wr*64 + mi*16 + ((lane >> 4) << 2);
      int col = n0 + wc*64 + ni*16 + (lane & 15);
      #pragma unroll
      for (int j = 0; j < 4; ++j)
        outb[(size_t)(lrow + j)*G4c + col] = (bf16)(acc[mi][ni][j] + p0[col]);
    }
}

// ---------------- fused persistent LSTM recurrence + FC GEMM ----------------
// 256 blocks x 256 threads, 1 block/CU. Block (strip 0..127, rh 0..1).
// Phase 1 (persist): R12 structure. Hall stores now WRITE-THROUGH + per-(t,half)
// completion counters hallflg (target 128); blocks bump never-produce slots at exit.
// Phase 2 (FC): finished blocks become FC-tile workers: atomic tile queue (mt-major,
// matching t-major availability), per-tile gate on hallflg[tmax] both halves,
// 2-phase double-buffered K-loop (stage k+1 overlap compute k, counted own-vmcnt).

__global__ __launch_bounds__(256, 1) void lstm_persist(
  const bf16* __restrict__ Whi, const bf16* __restrict__ Wlo,
  const bf16* __restrict__ Xg,
  bf16* __restrict__ hCh, bf16* __restrict__ hCl,
  bf16* __restrict__ Hh, bf16* __restrict__ Hl,
  const bf16* __restrict__ WfcHi, const bf16* __restrict__ WfcLo,
  const float* __restrict__ bfc,
  const int* __restrict__ lens, const int* __restrict__ meta,
  float* __restrict__ outf,
  int* __restrict__ flg)      // [0,256) chain flags; [256,316) hallflg; [320] tilectr
{
  extern __shared__ char sWc[];    // 64KB hi chunks + 64KB lo chunks + 2KB scratch + ctrl
  int tid = threadIdx.x, lane = tid & 63, w = tid >> 6;
  int bid = blockIdx.x;
  int strip = bid >> 1, rh = bid & 1;
  int pc0 = strip * 32;
  int row0 = rh * 64 + w * 16;
  int grp = strip >> 5;
  char* scr = sWc + 131072 + w*512;   // per-wave: hi [16][8] @0, lo @256
  int* hallflg = flg + 256;
  int* tilectr = flg + 320;

  // ---- fill W slice into LDS: chunk (ks,ni) holds lanes' fragments linearly ----
  for (int ch = tid; ch < 4096; ch += 256) {
    int p = ch >> 7;              // 0..31 = ni*16 + bp
    int k = (ch & 127) * 8;       // 0..1016
    int ni = p >> 4, bp = p & 15;
    int ks = k >> 5, kg = (k >> 3) & 3;
    int off = (((ks*2 + ni)*4 + kg)*16 + bp) * 16;
    bf16x8 vh = *(const bf16x8*)&Whi[(size_t)(pc0 + p)*Hc + k];
    bf16x8 vl = *(const bf16x8*)&Wlo[(size_t)(pc0 + p)*Hc + k];
    *(bf16x8*)(sWc + off) = vh;
    *(bf16x8*)(sWc + 65536 + off) = vl;
  }
  __syncthreads();

  int bp = lane & 15;
  int bk = (lane >> 4) << 3;
  int rbase = row0 + ((lane >> 4) << 2);
  int e = lane & 3;
  const char* sWhiB = sWc + lane*16;           // linear per-lane base (hi)
  const char* sWloB = sWc + 65536 + lane*16;   // (lo)

  int Lh = lens[rh * 64];
  if (Lh > NSTEP) Lh = NSTEP;
  int lenv = lens[row0 + (lane & 15)] - 1;   // used by Hall lanes (32-63)

  float creg[2] = {0.f, 0.f};
  float xgv[2][4];
  #pragma unroll
  for (int ni = 0; ni < 2; ++ni)
    #pragma unroll
    for (int j = 0; j < 4; ++j)
      xgv[ni][j] = (float)Xg[(size_t)(rbase + j)*G4c + pc0 + ni*16 + bp];

#define GATEQ(g, fg) do { if (s > 0) { \
    if (tid == 0 && (fg) < 32) waitflag(&flg[(s*2 + rh)*4 + (g)], 32); \
    __builtin_amdgcn_s_barrier(); \
    asm volatile("" ::: "memory"); } } while (0)

#define LOADQ(qh, ql, g) do { \
    _Pragma("unroll") \
    for (int i = 0; i < 8; ++i) { \
      qh[i] = *(const bf16x8*)(pah + ((g)*8 + i)*32); \
      ql[i] = *(const bf16x8*)(pal + ((g)*8 + i)*32); \
    } \
    asm volatile("" ::: "memory"); } while (0)

#define MFMAQ(qh, ql, g) do { \
    _Pragma("unroll") \
    for (int i = 0; i < 8; ++i) { \
      int ks = (g)*8 + i; \
      _Pragma("unroll") \
      for (int ni = 0; ni < 2; ++ni) { \
        bf16x8 bvh = *(const bf16x8*)(sWhiB + (ks*2 + ni)*1024); \
        bf16x8 bvl = *(const bf16x8*)(sWloB + (ks*2 + ni)*1024); \
        aHH[ni] = MFMA_B16(qh[i], bvh, aHH[ni]); \
        aHL[ni] = MFMA_B16(qh[i], bvl, aHL[ni]); \
        aLH[ni] = MFMA_B16(ql[i], bvh, aLH[ni]); \
      } \
    } } while (0)

  #pragma unroll 1
  for (int s = 0; s < Lh; ++s) {
    const bf16* pah = hCh + (size_t)s*Bc*Hc + (size_t)(row0 + bp)*Hc + bk;
    const bf16* pal = hCl + (size_t)s*Bc*Hc + (size_t)(row0 + bp)*Hc + bk;
    bf16* hwh = hCh + (size_t)(s+1)*Bc*Hc;
    bf16* hwl = hCl + (size_t)(s+1)*Bc*Hc;

    f32x4 aHH[2], aHL[2], aLH[2];
    #pragma unroll
    for (int ni = 0; ni < 2; ++ni) {
      #pragma unroll
      for (int j = 0; j < 4; ++j) aHH[ni][j] = xgv[ni][j];
      aHL[ni] = (f32x4){0.f,0.f,0.f,0.f};
      aLH[ni] = (f32x4){0.f,0.f,0.f,0.f};
    }

    bf16x8 qh0[8], ql0[8], qh1[8], ql1[8];
    int f1 = 32, f2 = 32, f3 = 32;

    if (s > 0) {
      if (tid == 0) waitflags4(&flg[(s*2 + rh)*4], f1, f2, f3);
      __builtin_amdgcn_s_barrier();
      asm volatile("" ::: "memory");
    }
    LOADQ(qh0, ql0, 0);
    GATEQ(1, f1); LOADQ(qh1, ql1, 1);
    MFMAQ(qh0, ql0, 0);
    GATEQ(2, f2); LOADQ(qh0, ql0, 2);
    MFMAQ(qh1, ql1, 1);
    GATEQ(3, f3); LOADQ(qh1, ql1, 3);
    MFMAQ(qh0, ql0, 2);
    MFMAQ(qh1, ql1, 3);

    // ---- lane-specialized LSTM epilogue: lane e owns row rbase+e ----
    #pragma unroll
    for (int ni = 0; ni < 2; ++ni) {
      float v0 = aHH[ni][0] + aHL[ni][0] + aLH[ni][0];
      float v1 = aHH[ni][1] + aHL[ni][1] + aLH[ni][1];
      float v2 = aHH[ni][2] + aHL[ni][2] + aLH[ni][2];
      float v3 = aHH[ni][3] + aHL[ni][3] + aLH[ni][3];
      float g0 = sel4(v0, v1, v2, v3, e);
      float g1 = __shfl_xor(sel4(v0, v1, v2, v3, e ^ 1), 1);
      float g2 = __shfl_xor(sel4(v0, v1, v2, v3, e ^ 2), 2);
      float g3 = __shfl_xor(sel4(v0, v1, v2, v3, e ^ 3), 3);
      float gI = sel4(g0, g1, g2, g3, e);
      float gF = sel4(g0, g1, g2, g3, e ^ 1);
      float gG = sel4(g0, g1, g2, g3, e ^ 2);
      float gO = sel4(g0, g1, g2, g3, e ^ 3);

      float co = creg[ni];
      float cn = fsigm(gF)*co + fsigm(gI)*ftanh(gG);
      float hn = fsigm(gO)*ftanh(cn);
      creg[ni] = cn;
      bf16 hhi = (bf16)hn;
      int r16 = ((lane >> 4) << 2) + e;
      int c8  = ni*4 + (bp >> 2);
      *(bf16*)(scr + (r16*8 + c8)*2) = hhi;
      *(bf16*)(scr + 256 + (r16*8 + c8)*2) = (bf16)(hn - (float)hhi);
    }

    asm volatile("s_waitcnt lgkmcnt(0)" ::: "memory");
    __builtin_amdgcn_sched_barrier(0);

    // lanes 0-31: coalesced 16B write-through chain stores
    if (lane < 32) {
      int r = lane & 15, buf = lane >> 4;
      bf16x8 vv = *(const bf16x8*)(scr + buf*256 + r*16);
      bf16* dst = (buf ? hwl : hwh) + (size_t)(row0 + r)*Hc + strip*8;
      wt16(dst, vv);
    }

    __syncthreads();                 // drains chain stores for whole block
    if (tid == 0 && s + 1 < Lh)
      __hip_atomic_fetch_add(&flg[((s+1)*2 + rh)*4 + grp], 1,
                             __ATOMIC_RELAXED, __HIP_MEMORY_SCOPE_AGENT);

    // ---- off-path: Hall WRITE-THROUGH stores (lanes 32-63, masked) + Xg prefetch ----
    if (s > 0 && lane >= 32 && (s - 1) < lenv) {
      int r = lane & 15, buf = (lane >> 4) & 1;
      bf16x8 vv = *(const bf16x8*)(scr + buf*256 + r*16);
      wt16((buf ? Hl : Hh) + (size_t)((s-1)*Bc + row0 + r)*Hc + strip*8, vv);
    }
    if (s + 1 < Lh) {
      #pragma unroll
      for (int ni = 0; ni < 2; ++ni)
        #pragma unroll
        for (int j = 0; j < 4; ++j)
          xgv[ni][j] = (float)Xg[(size_t)((s+1)*Bc + rbase + j)*G4c + pc0 + ni*16 + bp];
    }

    __syncthreads();                 // drains Hall stores
    if (tid == 0 && s > 0)
      __hip_atomic_fetch_add(&hallflg[(s-1)*2 + rh], 1,
                             __ATOMIC_RELAXED, __HIP_MEMORY_SCOPE_AGENT);
  }
#undef GATEQ
#undef LOADQ
#undef MFMAQ

  // ---- never-produce signals: this block writes Hall[t] only for t < Lh-1 ----
  if (tid == 0)
    for (int t = Lh - 1; t < TMAXc; ++t)
      __hip_atomic_fetch_add(&hallflg[t*2 + rh], 1,
                             __ATOMIC_RELAXED, __HIP_MEMORY_SCOPE_AGENT);

  __syncthreads();   // all waves done with persist LDS

  // ================= FC mode =================
  bf16* sAh2 = (bf16*)(sWc);            // [2][128*32] dbuf
  bf16* sBh2 = (bf16*)(sWc + 32768);
  bf16* sAl2 = (bf16*)(sWc + 65536);
  bf16* sBl2 = (bf16*)(sWc + 98304);
  int* ctrl  = (int*)(sWc + 131072 + 2044);

  int R = meta[0];
  int mtilesFC = (R + 127) >> 7;
  int ntFC = mtilesFC * 79;
  int wr = w >> 1, wc2 = w & 1;

#define STAGE_FC(buf, kt) do { \
    _Pragma("unroll") \
    for (int is = 0; is < 2; ++is) { \
      int p = tid*16 + is*4096; \
      int c = (p & 63) >> 1; \
      int r = p >> 6; \
      int ldsoff = (buf)*4096 + w*512 + is*2048; \
      int ga = is ? gr1 : gr0; \
      int rb = n0 + r; if (rb > 9999) rb = 9999; \
      gll16(Hh + (size_t)ga*Hc + (kt) + c, &sAh2[ldsoff]); \
      gll16(WfcHi + (size_t)rb*Hc + (kt) + c, &sBh2[ldsoff]); \
      gll16(Hl + (size_t)ga*Hc + (kt) + c, &sAl2[ldsoff]); \
      gll16(WfcLo + (size_t)rb*Hc + (kt) + c, &sBl2[ldsoff]); \
    } } while (0)

  #pragma unroll 1
  for (;;) {
    if (tid == 0) ctrl[0] = __hip_atomic_fetch_add(tilectr, 1,
                               __ATOMIC_RELAXED, __HIP_MEMORY_SCOPE_AGENT);
    __syncthreads();
    int idx = ctrl[0];
    __syncthreads();
    if (idx >= ntFC) break;
    int mt = idx / 79, ntc = idx - mt*79;
    int m0 = mt*128, n0 = ntc*128;
    int last = m0 + 127; if (last >= R) last = R - 1;
    int tmax = meta[1 + last] >> 7;
    if (tid == 0) {
      waitflag(&hallflg[tmax*2 + 0], 128);
      waitflag(&hallflg[tmax*2 + 1], 128);
    }
    __builtin_amdgcn_s_barrier();
    asm volatile("" ::: "memory");

    int sr = (tid*16) >> 6;
    int gr0 = meta[1 + m0 + sr], gr1 = meta[1 + m0 + sr + 64];

    f32x4 acc[4][4] = {};

    STAGE_FC(0, 0);
    asm volatile("s_waitcnt vmcnt(0)" ::: "memory");
    __builtin_amdgcn_s_barrier();
    asm volatile("" ::: "memory");

    #pragma unroll 1
    for (int ks = 0; ks < 32; ++ks) {
      int buf = ks & 1;
      if (ks + 1 < 32) STAGE_FC(buf ^ 1, (ks+1)*32);   // overlap with compute

      int koff = (lane >> 4) * 8;
      int bb = buf*4096;
      bf16x8 ah[4], bh[4], al[4], bl[4];
      #pragma unroll
      for (int mi = 0; mi < 4; ++mi) {
        int rr = wr*64 + mi*16 + (lane & 15);
        ah[mi] = *(const bf16x8*)&sAh2[bb + rr*32 + koff];
        al[mi] = *(const bf16x8*)&sAl2[bb + rr*32 + koff];
      }
      #pragma unroll
      for (int ni = 0; ni < 4; ++ni) {
        int rr = wc2*64 + ni*16 + (lane & 15);
        bh[ni] = *(const bf16x8*)&sBh2[bb + rr*32 + koff];
        bl[ni] = *(const bf16x8*)&sBl2[bb + rr*32 + koff];
      }
      #pragma unroll
      for (int mi = 0; mi < 4; ++mi)
        #pragma unroll
        for (int ni = 0; ni < 4; ++ni) {
          acc[mi][ni] = MFMA_B16(ah[mi], bh[ni], acc[mi][ni]);
          acc[mi][ni] = MFMA_B16(ah[mi], bl[ni], acc[mi][ni]);
          acc[mi][ni] = MFMA_B16(al[mi], bh[ni], acc[mi][ni]);
        }

      asm volatile("s_waitcnt vmcnt(0)" ::: "memory");  // own next-buf loads arrived
      __builtin_amdgcn_s_barrier();                      // everyone done reading buf
      asm volatile("" ::: "memory");
    }

    // epilogue: scatter to out via meta
    #pragma unroll
    for (int mi = 0; mi < 4; ++mi)
      #pragma unroll
      for (int ni = 0; ni < 4; ++ni) {
        int lrow = m0 + wr*64 + mi*16 + ((lane >> 4) << 2);
        int col = n0 + wc2*64 + ni*16 + (lane & 15);
        #pragma unroll
        for (int j = 0; j < 4; ++j) {
          int rr = lrow + j;
          if (rr < R && col < Vc) {
            int val = meta[1 + rr];
            int t = val >> 7, b = val & 127;
            outf[(size_t)b*(TMAXc*Vc) + (size_t)t*Vc + col] = acc[mi][ni][j] + bfc[col];
          }
        }
      }
  }
#undef STAGE_FC
}

// ---------------- launch ----------------

extern "C" void kernel_launch(void* const* d_in, const int* in_sizes, int n_in,
                              void* d_out, int out_size, void* d_ws, size_t ws_size,
                              hipStream_t stream)
{
  const float* enc   = (const float*)d_in[0];
  const int*   gt    = (const int*)  d_in[1];
  const int*   lens  = (const int*)  d_in[2];
  const float* emb   = (const float*)d_in[3];
  const float* Winit = (const float*)d_in[4];
  const float* binit = (const float*)d_in[5];
  const float* gam   = (const float*)d_in[6];
  const float* bet   = (const float*)d_in[7];
  const float* Wih   = (const float*)d_in[8];
  const float* bih   = (const float*)d_in[9];
  const float* Whh   = (const float*)d_in[10];
  const float* bhh   = (const float*)d_in[11];
  const float* Wfc   = (const float*)d_in[12];
  const float* bfc   = (const float*)d_in[13];
  float* out = (float*)d_out;

  char* ws = (char*)d_ws;
  size_t off = 0;
  auto alloc = [&](size_t bytes) -> char* {
    char* p = ws + off;
    off += (bytes + 255) & ~(size_t)255;
    return p;
  };

  bf16* featB  = (bf16*)alloc((size_t)Bc*Fc*2);
  bf16* WinitB = (bf16*)alloc((size_t)Ec*Fc*2);
  bf16* WihpB  = (bf16*)alloc((size_t)G4c*Ec*2);
  bf16* WhhHi  = (bf16*)alloc((size_t)G4c*Hc*2);
  bf16* WhhLo  = (bf16*)alloc((size_t)G4c*Hc*2);
  bf16* WfcHi  = (bf16*)alloc((size_t)Vc*Hc*2);
  bf16* WfcLo  = (bf16*)alloc((size_t)Vc*Hc*2);
  float* bcomb = (float*)alloc((size_t)G4c*4);
  bf16* Xall   = (bf16*)alloc((size_t)MALLc*Ec*2);
  bf16* Xg     = (bf16*)alloc((size_t)MALLc*G4c*2);
  bf16* hChH   = (bf16*)alloc((size_t)(NSTEP+1)*Bc*Hc*2);
  bf16* hChL   = (bf16*)alloc((size_t)(NSTEP+1)*Bc*Hc*2);
  bf16* HallH  = (bf16*)alloc((size_t)MOUTc*Hc*2);
  bf16* HallL  = (bf16*)alloc((size_t)MOUTc*Hc*2);
  float* part  = (float*)alloc((size_t)8*128*512*4);
  int*  meta   = (int*) alloc((size_t)(1 + MOUTc)*4);
  int*  flg    = (int*) alloc((size_t)384*4);

  if (off > ws_size) return;

  hipMemsetAsync(hChH, 0, (size_t)Bc*Hc*2, stream);
  hipMemsetAsync(hChL, 0, (size_t)Bc*Hc*2, stream);
  hipMemsetAsync(flg, 0, (size_t)384*4, stream);

  mean_kernel<<<256, 256, 0, stream>>>(enc, featB);
  conv_kernel<<<(Ec*Fc/4 + 255)/256, 256, 0, stream>>>(Winit, WinitB, Ec*Fc/4);
  permconv_ih<<<(G4c*Ec/4 + 255)/256, 256, 0, stream>>>(Wih, WihpB);
  permsplit_hh<<<(G4c*Hc/4 + 255)/256, 256, 0, stream>>>(Whh, WhhHi, WhhLo);
  split_kernel<<<(Vc*Hc/4 + 255)/256, 256, 0, stream>>>(Wfc, WfcHi, WfcLo, Vc*Hc/4);
  bcomb_kernel<<<(G4c + 255)/256, 256, 0, stream>>>(bih, bhh, bcomb);
  gather_kernel<<<(MOUTc*(Ec/4) + 255)/256, 256, 0, stream>>>(emb, gt, Xall);
  build_ridx<<<(MOUTc + 255)/256, 256, 0, stream>>>(lens, meta);
  zerofill<<<(MOUTc*2500 + 255)/256, 256, 0, stream>>>(lens, out);

  initA<<<32, 256, 0, stream>>>(featB, WinitB, part);
  initB<<<(128*512 + 255)/256, 256, 0, stream>>>(part, binit, gam, bet, Xall);

  gemm_xg<<<31*32, 256, 0, stream>>>(
      Xall, WihpB, MALLc, G4c, Ec, 31, bcomb, Xg);

  hipFuncSetAttribute(reinterpret_cast<const void*>(lstm_persist),
                      hipFuncAttributeMaxDynamicSharedMemorySize, 133120);
  lstm_persist<<<NBLK, 256, 133120, stream>>>(
      WhhHi, WhhLo, Xg, hChH, hChL, HallH, HallL,
      WfcHi, WfcLo, bfc, lens, meta, out, flg);
}

// Round 15
// 619.583 us; speedup vs baseline: 1.0539x; 1.0539x over previous
//
#include <hip/hip_runtime.h>
#include <math.h>

typedef __bf16 bf16;
typedef __bf16 bf16x8 __attribute__((ext_vector_type(8)));
typedef __bf16 bf16x4 __attribute__((ext_vector_type(4)));
typedef float f32x4 __attribute__((ext_vector_type(4)));

#define MFMA_B16(a,b,c) __builtin_amdgcn_mfma_f32_16x16x32_bf16((a),(b),(c),0,0,0)

constexpr int TMAXc = 30;
constexpr int Bc = 128, Pc = 196, Fc = 2048, Ec = 512, Hc = 1024, Vc = 10000;
constexpr int G4c = 4 * Hc;          // 4096
constexpr int NSTEP = TMAXc + 1;     // 31
constexpr int MALLc = NSTEP * Bc;    // 3968
constexpr int MOUTc = TMAXc * Bc;    // 3840
constexpr int NBLK = 256;            // persistent kernel grid

__device__ __forceinline__ float fsigm(float x){
  return __fdividef(1.0f, 1.0f + __expf(-x));
}
__device__ __forceinline__ float ftanh(float x){
  return 1.0f - __fdividef(2.0f, __expf(2.0f*x) + 1.0f);
}
// 4-way select by runtime index (3 cndmask, no scratch - rule #20 safe)
__device__ __forceinline__ float sel4(float a, float b, float c, float d, int i){
  float x = (i & 1) ? b : a;
  float y = (i & 1) ? d : c;
  return (i & 2) ? y : x;
}

__device__ __forceinline__ void gll16(const void* g, void* l){
  __builtin_amdgcn_global_load_lds((const __attribute__((address_space(1))) void*)g,
                                   (__attribute__((address_space(3))) void*)l, 16, 0, 0);
}

// 16B write-through store (bypasses L1/L2, lands at coherence point / MALL)
__device__ __forceinline__ void wt16(bf16* p, bf16x8 v){
  asm volatile("global_store_dwordx4 %0, %1, off sc0 sc1" :: "v"(p), "v"(v) : "memory");
}

__device__ __forceinline__ int aldf(int* f){
  return __hip_atomic_load(f, __ATOMIC_RELAXED, __HIP_MEMORY_SCOPE_AGENT);
}

// bounded spin: escapes after ~1ms (s_memrealtime = 100 MHz const clock)
__device__ __forceinline__ void waitflag(int* f, int tgt){
  long long t0 = __builtin_amdgcn_s_memrealtime();
  while (aldf(f) < tgt) {
    __builtin_amdgcn_s_sleep(1);
    if (__builtin_amdgcn_s_memrealtime() - t0 > 100000) break;
  }
}

// poll gate0 while snapshotting gates 1-3 in the same round trip
__device__ __forceinline__ void waitflags4(int* F, int& f1, int& f2, int& f3){
  long long t0 = __builtin_amdgcn_s_memrealtime();
  for (;;) {
    int f0 = aldf(F + 0);
    f1 = aldf(F + 1);
    f2 = aldf(F + 2);
    f3 = aldf(F + 3);
    if (f0 >= 32) break;
    __builtin_amdgcn_s_sleep(1);
    if (__builtin_amdgcn_s_memrealtime() - t0 > 100000) break;
  }
}

// ---------------- prep kernels ----------------

__global__ void mean_kernel(const float* __restrict__ enc, bf16* __restrict__ feat){
  int blk = blockIdx.x, b = blk >> 1, half = blk & 1;
  int f0 = half*1024 + threadIdx.x*4;
  const float* p = enc + (size_t)b*Pc*Fc + f0;
  float4 s = {0.f,0.f,0.f,0.f};
  #pragma unroll 4
  for (int q = 0; q < Pc; ++q) {
    float4 v = *(const float4*)(p + (size_t)q*Fc);
    s.x += v.x; s.y += v.y; s.z += v.z; s.w += v.w;
  }
  const float r = 1.0f/(float)Pc;
  bf16x4 o = { (bf16)(s.x*r), (bf16)(s.y*r), (bf16)(s.z*r), (bf16)(s.w*r) };
  *(bf16x4*)&feat[b*Fc + f0] = o;
}

__global__ void conv_kernel(const float* __restrict__ src, bf16* __restrict__ dst, int n4){
  int i = blockIdx.x*256 + threadIdx.x;
  if (i >= n4) return;
  float4 v = ((const float4*)src)[i];
  bf16x4 o = { (bf16)v.x, (bf16)v.y, (bf16)v.z, (bf16)v.w };
  *(bf16x4*)&dst[i*4] = o;
}

__global__ void permconv_ih(const float* __restrict__ W, bf16* __restrict__ Wp){
  int i = blockIdx.x*256 + threadIdx.x;
  if (i >= G4c*Ec/4) return;
  int i4 = i*4;
  int rp = i4 >> 9, k = i4 & 511;
  int g = rp & 3, j = rp >> 2;
  float4 v = *(const float4*)&W[(size_t)(g*Hc + j)*Ec + k];
  bf16x4 o = { (bf16)v.x, (bf16)v.y, (bf16)v.z, (bf16)v.w };
  *(bf16x4*)&Wp[i4] = o;
}

__global__ void permsplit_hh(const float* __restrict__ W, bf16* __restrict__ Whi, bf16* __restrict__ Wlo){
  int i = blockIdx.x*256 + threadIdx.x;
  if (i >= G4c*Hc/4) return;
  int i4 = i*4;
  int rp = i4 >> 10, k = i4 & 1023;
  int g = rp & 3, j = rp >> 2;
  float4 v = *(const float4*)&W[(size_t)(g*Hc + j)*Hc + k];
  bf16 h0=(bf16)v.x, h1=(bf16)v.y, h2=(bf16)v.z, h3=(bf16)v.w;
  bf16x4 hi = { h0, h1, h2, h3 };
  bf16x4 lo = { (bf16)(v.x-(float)h0), (bf16)(v.y-(float)h1), (bf16)(v.z-(float)h2), (bf16)(v.w-(float)h3) };
  *(bf16x4*)&Whi[i4] = hi;
  *(bf16x4*)&Wlo[i4] = lo;
}

__global__ void split_kernel(const float* __restrict__ W, bf16* __restrict__ Whi, bf16* __restrict__ Wlo, int n4){
  int i = blockIdx.x*256 + threadIdx.x;
  if (i >= n4) return;
  float4 v = ((const float4*)W)[i];
  bf16 h0=(bf16)v.x, h1=(bf16)v.y, h2=(bf16)v.z, h3=(bf16)v.w;
  bf16x4 hi = { h0, h1, h2, h3 };
  bf16x4 lo = { (bf16)(v.x-(float)h0), (bf16)(v.y-(float)h1), (bf16)(v.z-(float)h2), (bf16)(v.w-(float)h3) };
  *(bf16x4*)&Whi[i*4] = hi;
  *(bf16x4*)&Wlo[i*4] = lo;
}

__global__ void bcomb_kernel(const float* __restrict__ bih, const float* __restrict__ bhh, float* __restrict__ bc){
  int i = blockIdx.x*256 + threadIdx.x;
  if (i >= G4c) return;
  int g = i & 3, j = i >> 2;
  bc[i] = bih[g*Hc + j] + bhh[g*Hc + j];
}

__global__ void gather_kernel(const float* __restrict__ emb, const int* __restrict__ gt, bf16* __restrict__ X){
  int idx = blockIdx.x*256 + threadIdx.x;
  if (idx >= MOUTc*(Ec/4)) return;
  int r = idx >> 7, ei = (idx & 127) * 4;
  int s = (r >> 7) + 1, b = r & 127;
  int tok = gt[b*(TMAXc+1) + (s-1)];
  float4 v = *(const float4*)(emb + (size_t)tok*Ec + ei);
  bf16x4 o = { (bf16)v.x, (bf16)v.y, (bf16)v.z, (bf16)v.w };
  *(bf16x4*)&X[(size_t)(s*Bc + b)*Ec + ei] = o;
}

__global__ void build_ridx(const int* __restrict__ lens, int* __restrict__ meta){
  int i = blockIdx.x*256 + threadIdx.x;
  if (i >= MOUTc) return;
  int t = i >> 7, b = i & 127;
  int S = 0, R = 0;
  for (int bb = 0; bb < 128; ++bb) {
    int l = lens[bb] - 1;
    S += (t < l) ? t : l;
    R += l;
  }
  if (i == 0) meta[0] = R;
  if (i >= R) meta[1 + i] = 0;
  if (t < lens[b] - 1) meta[1 + S + b] = i;
}

__global__ void zerofill(const int* __restrict__ lens, float* __restrict__ out){
  int i = blockIdx.x*256 + threadIdx.x;
  if (i >= MOUTc*2500) return;
  int row = i / 2500, c4 = i - row*2500;
  int b = row / TMAXc, t = row - b*TMAXc;
  if (t >= lens[b] - 1) {
    float4 z = {0.f,0.f,0.f,0.f};
    *(float4*)(out + (size_t)row*Vc + c4*4) = z;
  }
}

// ---------------- GEMM A split-K: x0 partials (32 blocks = 4 ntiles x 8 kchunks) ----------
__global__ __launch_bounds__(256, 2) void initA(
  const bf16* __restrict__ feat, const bf16* __restrict__ Wi, float* __restrict__ part)
{
  __shared__ alignas(16) bf16 sA[128*32], sB[128*32];
  int tid = threadIdx.x, lane = tid & 63, w = tid >> 6, wr = w >> 1, wc = w & 1;
  int nt = blockIdx.x & 3, kc = blockIdx.x >> 2;
  int n0 = nt*128;

  f32x4 acc[4][4] = {};
  for (int kt = kc*256; kt < kc*256 + 256; kt += 32) {
    #pragma unroll
    for (int is = 0; is < 2; ++is) {
      int p = tid*16 + is*4096;
      int r = p >> 6, c = (p & 63) >> 1;
      int ldsoff = w*512 + is*2048;
      gll16(feat + (size_t)r*Fc + kt + c, &sA[ldsoff]);
      gll16(Wi + (size_t)(n0 + r)*Fc + kt + c, &sB[ldsoff]);
    }
    __syncthreads();
    int koff = (lane >> 4) * 8;
    bf16x8 ah[4], bh[4];
    #pragma unroll
    for (int mi = 0; mi < 4; ++mi)
      ah[mi] = *(const bf16x8*)&sA[(wr*64 + mi*16 + (lane & 15))*32 + koff];
    #pragma unroll
    for (int ni = 0; ni < 4; ++ni)
      bh[ni] = *(const bf16x8*)&sB[(wc*64 + ni*16 + (lane & 15))*32 + koff];
    #pragma unroll
    for (int mi = 0; mi < 4; ++mi)
      #pragma unroll
      for (int ni = 0; ni < 4; ++ni)
        acc[mi][ni] = MFMA_B16(ah[mi], bh[ni], acc[mi][ni]);
    __syncthreads();
  }
  #pragma unroll
  for (int mi = 0; mi < 4; ++mi)
    #pragma unroll
    for (int ni = 0; ni < 4; ++ni) {
      int lrow = wr*64 + mi*16 + ((lane >> 4) << 2);
      int col = n0 + wc*64 + ni*16 + (lane & 15);
      #pragma unroll
      for (int j = 0; j < 4; ++j)
        part[((size_t)kc*128 + lrow + j)*512 + col] = acc[mi][ni][j];
    }
}

__global__ void initB(const float* __restrict__ part, const float* __restrict__ binit,
                      const float* __restrict__ gam, const float* __restrict__ bet,
                      bf16* __restrict__ Xall)
{
  int i = blockIdx.x*256 + threadIdx.x;
  if (i >= 128*512) return;
  int col = i & 511;
  float v = 0.f;
  #pragma unroll
  for (int kc = 0; kc < 8; ++kc) v += part[(size_t)kc*128*512 + i];
  const float rbn = rsqrtf(1.0f + 1e-5f);
  v = fsigm(v + binit[col]);
  v = gam[col]*(v*rbn) + bet[col];
  Xall[i] = (bf16)v;
}

// ---------------- Xg GEMM (128x128 tile, BK=32, nt-major, XCD swizzle) --------
__global__ __launch_bounds__(256, 2) void gemm_xg(
  const bf16* __restrict__ A, const bf16* __restrict__ B,
  int M, int N, int K, int mtiles,
  const float* __restrict__ p0, bf16* __restrict__ outb)
{
  constexpr int BK = 32;
  __shared__ alignas(16) bf16 sAh[128*BK], sBh[128*BK];

  int tid = threadIdx.x;
  int lane = tid & 63, w = tid >> 6, wr = w >> 1, wc = w & 1;
  int bid = blockIdx.x;
  {
    int nwg = gridDim.x, q = nwg >> 3, r = nwg & 7;
    int x = bid & 7, o = bid >> 3;
    bid = (x < r ? x*(q+1) : r*(q+1) + (x-r)*q) + o;
  }
  int nt = bid / mtiles, mt = bid - nt*mtiles;
  int m0 = mt*128, n0 = nt*128;

  int sr = (tid*16) >> 6;
  int gr0 = m0 + sr, gr1 = m0 + sr + 64;

  f32x4 acc[4][4] = {};

  for (int kt = 0; kt < K; kt += BK) {
    #pragma unroll
    for (int is = 0; is < 2; ++is) {
      int p = tid*16 + is*4096;
      int c = (p & 63) >> 1;
      int r = p >> 6;
      int ldsoff = w*512 + is*2048;
      int ga = is ? gr1 : gr0;
      gll16(A + (size_t)ga*K + kt + c, &sAh[ldsoff]);
      gll16(B + (size_t)(n0 + r)*K + kt + c, &sBh[ldsoff]);
    }
    __syncthreads();

    int koff = (lane >> 4) * 8;
    bf16x8 ah[4], bh[4];
    #pragma unroll
    for (int mi = 0; mi < 4; ++mi)
      ah[mi] = *(const bf16x8*)&sAh[(wr*64 + mi*16 + (lane & 15))*BK + koff];
    #pragma unroll
    for (int ni = 0; ni < 4; ++ni)
      bh[ni] = *(const bf16x8*)&sBh[(wc*64 + ni*16 + (lane & 15))*BK + koff];
    #pragma unroll
    for (int mi = 0; mi < 4; ++mi)
      #pragma unroll
      for (int ni = 0; ni < 4; ++ni)
        acc[mi][ni] = MFMA_B16(ah[mi], bh[ni], acc[mi][ni]);
    __syncthreads();
  }

  #pragma unroll
  for (int mi = 0; mi < 4; ++mi)
    #pragma unroll
    for (int ni = 0; ni < 4; ++ni) {
      int lrow = m0 + wr*64 + mi*16 + ((lane >> 4) << 2);
      int col = n0 + wc*64 + ni*16 + (lane & 15);
      #pragma unroll
      for (int j = 0; j < 4; ++j)
        outb[(size_t)(lrow + j)*G4c + col] = (bf16)(acc[mi][ni][j] + p0[col]);
    }
}

// ---------------- fused persistent LSTM recurrence + FC GEMM ----------------
// 256 blocks x 256 threads, 1 block/CU. Block (strip 0..127, rh 0..1).
// NEW vs R14: (1) persist back to ONE barrier/step: Hall WT stores stay off-path
// (after signal); hallflg[t] signaled one step late (drained by the next step's
// barrier); (2) FC mode: 4-buffer pipeline with COUNTED vmcnt (16/8/0 tail) ->
// 96KB in flight per CU instead of 32KB, load latency hidden under MFMA.

__global__ __launch_bounds__(256, 1) void lstm_persist(
  const bf16* __restrict__ Whi, const bf16* __restrict__ Wlo,
  const bf16* __restrict__ Xg,
  bf16* __restrict__ hCh, bf16* __restrict__ hCl,
  bf16* __restrict__ Hh, bf16* __restrict__ Hl,
  const bf16* __restrict__ WfcHi, const bf16* __restrict__ WfcLo,
  const float* __restrict__ bfc,
  const int* __restrict__ lens, const int* __restrict__ meta,
  float* __restrict__ outf,
  int* __restrict__ flg)      // [0,256) chain flags; [256,316) hallflg; [320] tilectr
{
  extern __shared__ char sWc[];
  int tid = threadIdx.x, lane = tid & 63, w = tid >> 6;
  int bid = blockIdx.x;
  int strip = bid >> 1, rh = bid & 1;
  int pc0 = strip * 32;
  int row0 = rh * 64 + w * 16;
  int grp = strip >> 5;
  char* scr = sWc + 131072 + w*512;   // per-wave: hi [16][8] @0, lo @256
  int* hallflg = flg + 256;
  int* tilectr = flg + 320;

  // ---- fill W slice into LDS: chunk (ks,ni) holds lanes' fragments linearly ----
  for (int ch = tid; ch < 4096; ch += 256) {
    int p = ch >> 7;
    int k = (ch & 127) * 8;
    int ni = p >> 4, bp = p & 15;
    int ks = k >> 5, kg = (k >> 3) & 3;
    int off = (((ks*2 + ni)*4 + kg)*16 + bp) * 16;
    bf16x8 vh = *(const bf16x8*)&Whi[(size_t)(pc0 + p)*Hc + k];
    bf16x8 vl = *(const bf16x8*)&Wlo[(size_t)(pc0 + p)*Hc + k];
    *(bf16x8*)(sWc + off) = vh;
    *(bf16x8*)(sWc + 65536 + off) = vl;
  }
  __syncthreads();

  int bp = lane & 15;
  int bk = (lane >> 4) << 3;
  int rbase = row0 + ((lane >> 4) << 2);
  int e = lane & 3;
  const char* sWhiB = sWc + lane*16;
  const char* sWloB = sWc + 65536 + lane*16;

  int Lh = lens[rh * 64];
  if (Lh > NSTEP) Lh = NSTEP;
  int lenv = lens[row0 + (lane & 15)] - 1;

  float creg[2] = {0.f, 0.f};
  float xgv[2][4];
  #pragma unroll
  for (int ni = 0; ni < 2; ++ni)
    #pragma unroll
    for (int j = 0; j < 4; ++j)
      xgv[ni][j] = (float)Xg[(size_t)(rbase + j)*G4c + pc0 + ni*16 + bp];

#define GATEQ(g, fg) do { if (s > 0) { \
    if (tid == 0 && (fg) < 32) waitflag(&flg[(s*2 + rh)*4 + (g)], 32); \
    __builtin_amdgcn_s_barrier(); \
    asm volatile("" ::: "memory"); } } while (0)

#define LOADQ(qh, ql, g) do { \
    _Pragma("unroll") \
    for (int i = 0; i < 8; ++i) { \
      qh[i] = *(const bf16x8*)(pah + ((g)*8 + i)*32); \
      ql[i] = *(const bf16x8*)(pal + ((g)*8 + i)*32); \
    } \
    asm volatile("" ::: "memory"); } while (0)

#define MFMAQ(qh, ql, g) do { \
    _Pragma("unroll") \
    for (int i = 0; i < 8; ++i) { \
      int ks = (g)*8 + i; \
      _Pragma("unroll") \
      for (int ni = 0; ni < 2; ++ni) { \
        bf16x8 bvh = *(const bf16x8*)(sWhiB + (ks*2 + ni)*1024); \
        bf16x8 bvl = *(const bf16x8*)(sWloB + (ks*2 + ni)*1024); \
        aHH[ni] = MFMA_B16(qh[i], bvh, aHH[ni]); \
        aHL[ni] = MFMA_B16(qh[i], bvl, aHL[ni]); \
        aLH[ni] = MFMA_B16(ql[i], bvh, aLH[ni]); \
      } \
    } } while (0)

  #pragma unroll 1
  for (int s = 0; s < Lh; ++s) {
    const bf16* pah = hCh + (size_t)s*Bc*Hc + (size_t)(row0 + bp)*Hc + bk;
    const bf16* pal = hCl + (size_t)s*Bc*Hc + (size_t)(row0 + bp)*Hc + bk;
    bf16* hwh = hCh + (size_t)(s+1)*Bc*Hc;
    bf16* hwl = hCl + (size_t)(s+1)*Bc*Hc;

    f32x4 aHH[2], aHL[2], aLH[2];
    #pragma unroll
    for (int ni = 0; ni < 2; ++ni) {
      #pragma unroll
      for (int j = 0; j < 4; ++j) aHH[ni][j] = xgv[ni][j];
      aHL[ni] = (f32x4){0.f,0.f,0.f,0.f};
      aLH[ni] = (f32x4){0.f,0.f,0.f,0.f};
    }

    bf16x8 qh0[8], ql0[8], qh1[8], ql1[8];
    int f1 = 32, f2 = 32, f3 = 32;

    if (s > 0) {
      if (tid == 0) waitflags4(&flg[(s*2 + rh)*4], f1, f2, f3);
      __builtin_amdgcn_s_barrier();
      asm volatile("" ::: "memory");
    }
    LOADQ(qh0, ql0, 0);
    GATEQ(1, f1); LOADQ(qh1, ql1, 1);
    MFMAQ(qh0, ql0, 0);
    GATEQ(2, f2); LOADQ(qh0, ql0, 2);
    MFMAQ(qh1, ql1, 1);
    GATEQ(3, f3); LOADQ(qh1, ql1, 3);
    MFMAQ(qh0, ql0, 2);
    MFMAQ(qh1, ql1, 3);

    // ---- lane-specialized LSTM epilogue: lane e owns row rbase+e ----
    #pragma unroll
    for (int ni = 0; ni < 2; ++ni) {
      float v0 = aHH[ni][0] + aHL[ni][0] + aLH[ni][0];
      float v1 = aHH[ni][1] + aHL[ni][1] + aLH[ni][1];
      float v2 = aHH[ni][2] + aHL[ni][2] + aLH[ni][2];
      float v3 = aHH[ni][3] + aHL[ni][3] + aLH[ni][3];
      float g0 = sel4(v0, v1, v2, v3, e);
      float g1 = __shfl_xor(sel4(v0, v1, v2, v3, e ^ 1), 1);
      float g2 = __shfl_xor(sel4(v0, v1, v2, v3, e ^ 2), 2);
      float g3 = __shfl_xor(sel4(v0, v1, v2, v3, e ^ 3), 3);
      float gI = sel4(g0, g1, g2, g3, e);
      float gF = sel4(g0, g1, g2, g3, e ^ 1);
      float gG = sel4(g0, g1, g2, g3, e ^ 2);
      float gO = sel4(g0, g1, g2, g3, e ^ 3);

      float co = creg[ni];
      float cn = fsigm(gF)*co + fsigm(gI)*ftanh(gG);
      float hn = fsigm(gO)*ftanh(cn);
      creg[ni] = cn;
      bf16 hhi = (bf16)hn;
      int r16 = ((lane >> 4) << 2) + e;
      int c8  = ni*4 + (bp >> 2);
      *(bf16*)(scr + (r16*8 + c8)*2) = hhi;
      *(bf16*)(scr + 256 + (r16*8 + c8)*2) = (bf16)(hn - (float)hhi);
    }

    asm volatile("s_waitcnt lgkmcnt(0)" ::: "memory");
    __builtin_amdgcn_sched_barrier(0);

    // lanes 0-31: coalesced 16B write-through chain stores
    if (lane < 32) {
      int r = lane & 15, buf = lane >> 4;
      bf16x8 vv = *(const bf16x8*)(scr + buf*256 + r*16);
      bf16* dst = (buf ? hwl : hwh) + (size_t)(row0 + r)*Hc + strip*8;
      wt16(dst, vv);
    }

    __syncthreads();   // drains this step's chain stores AND prev step's Hall stores
    if (tid == 0) {
      if (s + 1 < Lh)
        __hip_atomic_fetch_add(&flg[((s+1)*2 + rh)*4 + grp], 1,
                               __ATOMIC_RELAXED, __HIP_MEMORY_SCOPE_AGENT);
      if (s >= 2)
        __hip_atomic_fetch_add(&hallflg[(s-2)*2 + rh], 1,
                               __ATOMIC_RELAXED, __HIP_MEMORY_SCOPE_AGENT);
    }

    // ---- off-path: Hall WT stores (lanes 32-63, masked) + Xg prefetch ----
    if (s > 0 && lane >= 32 && (s - 1) < lenv) {
      int r = lane & 15, buf = (lane >> 4) & 1;
      bf16x8 vv = *(const bf16x8*)(scr + buf*256 + r*16);
      wt16((buf ? Hl : Hh) + (size_t)((s-1)*Bc + row0 + r)*Hc + strip*8, vv);
    }
    if (s + 1 < Lh) {
      #pragma unroll
      for (int ni = 0; ni < 2; ++ni)
        #pragma unroll
        for (int j = 0; j < 4; ++j)
          xgv[ni][j] = (float)Xg[(size_t)((s+1)*Bc + rbase + j)*G4c + pc0 + ni*16 + bp];
    }
  }
#undef GATEQ
#undef LOADQ
#undef MFMAQ

  __syncthreads();   // drains final Hall stores (t = Lh-2)
  if (tid == 0) {
    if (Lh >= 2)
      __hip_atomic_fetch_add(&hallflg[(Lh-2)*2 + rh], 1,
                             __ATOMIC_RELAXED, __HIP_MEMORY_SCOPE_AGENT);
    for (int t = Lh - 1; t < TMAXc; ++t)
      __hip_atomic_fetch_add(&hallflg[t*2 + rh], 1,
                             __ATOMIC_RELAXED, __HIP_MEMORY_SCOPE_AGENT);
  }

  // ================= FC mode (4-buffer counted-vmcnt pipeline) =================
  bf16* L = (bf16*)sWc;   // buf b (0..3) @ b*16384 elems: Ahi@0 Bhi@4096 Alo@8192 Blo@12288
  int* ctrl = (int*)(sWc + 131072 + 2044);

  int R = meta[0];
  int mtilesFC = (R + 127) >> 7;
  int ntFC = mtilesFC * 79;
  int wr = w >> 1, wc2 = w & 1;

#define STAGE_FC(bufb, kt) do { \
    _Pragma("unroll") \
    for (int is = 0; is < 2; ++is) { \
      int p = tid*16 + is*4096; \
      int c = (p & 63) >> 1; \
      int r = p >> 6; \
      int eo = (bufb)*16384 + w*512 + is*2048; \
      int ga = is ? gr1 : gr0; \
      int rb = n0 + r; if (rb > 9999) rb = 9999; \
      gll16(Hh + (size_t)ga*Hc + (kt) + c, L + eo); \
      gll16(WfcHi + (size_t)rb*Hc + (kt) + c, L + 4096 + eo); \
      gll16(Hl + (size_t)ga*Hc + (kt) + c, L + 8192 + eo); \
      gll16(WfcLo + (size_t)rb*Hc + (kt) + c, L + 12288 + eo); \
    } } while (0)

  #pragma unroll 1
  for (;;) {
    if (tid == 0) ctrl[0] = __hip_atomic_fetch_add(tilectr, 1,
                               __ATOMIC_RELAXED, __HIP_MEMORY_SCOPE_AGENT);
    __syncthreads();
    int idx = ctrl[0];
    __syncthreads();
    if (idx >= ntFC) break;
    int mt = idx / 79, ntc = idx - mt*79;
    int m0 = mt*128, n0 = ntc*128;
    int last = m0 + 127; if (last >= R) last = R - 1;
    int tmax = meta[1 + last] >> 7;
    if (tid == 0) {
      waitflag(&hallflg[tmax*2 + 0], 128);
      waitflag(&hallflg[tmax*2 + 1], 128);
    }
    __builtin_amdgcn_s_barrier();
    asm volatile("" ::: "memory");

    int sr = (tid*16) >> 6;
    int gr0 = meta[1 + m0 + sr], gr1 = meta[1 + m0 + sr + 64];

    f32x4 acc[4][4] = {};

    STAGE_FC(0, 0);
    STAGE_FC(1, 32);
    STAGE_FC(2, 64);

    #pragma unroll 1
    for (int ks = 0; ks < 32; ++ks) {
      if (ks <= 29)      asm volatile("s_waitcnt vmcnt(16)" ::: "memory");
      else if (ks == 30) asm volatile("s_waitcnt vmcnt(8)"  ::: "memory");
      else               asm volatile("s_waitcnt vmcnt(0)"  ::: "memory");
      __builtin_amdgcn_s_barrier();      // all waves: buf ks ready, buf ks-1 reads done
      asm volatile("" ::: "memory");
      if (ks + 3 < 32) STAGE_FC((ks+3) & 3, (ks+3)*32);

      int koff = (lane >> 4) * 8;
      int bb = (ks & 3) * 16384;
      bf16x8 ah[4], bh[4], al[4], bl[4];
      #pragma unroll
      for (int mi = 0; mi < 4; ++mi) {
        int rr = wr*64 + mi*16 + (lane & 15);
        ah[mi] = *(const bf16x8*)&L[bb + rr*32 + koff];
        al[mi] = *(const bf16x8*)&L[bb + 8192 + rr*32 + koff];
      }
      #pragma unroll
      for (int ni = 0; ni < 4; ++ni) {
        int rr = wc2*64 + ni*16 + (lane & 15);
        bh[ni] = *(const bf16x8*)&L[bb + 4096 + rr*32 + koff];
        bl[ni] = *(const bf16x8*)&L[bb + 12288 + rr*32 + koff];
      }
      #pragma unroll
      for (int mi = 0; mi < 4; ++mi)
        #pragma unroll
        for (int ni = 0; ni < 4; ++ni) {
          acc[mi][ni] = MFMA_B16(ah[mi], bh[ni], acc[mi][ni]);
          acc[mi][ni] = MFMA_B16(ah[mi], bl[ni], acc[mi][ni]);
          acc[mi][ni] = MFMA_B16(al[mi], bh[ni], acc[mi][ni]);
        }
    }

    // epilogue: scatter to out via meta
    #pragma unroll
    for (int mi = 0; mi < 4; ++mi)
      #pragma unroll
      for (int ni = 0; ni < 4; ++ni) {
        int lrow = m0 + wr*64 + mi*16 + ((lane >> 4) << 2);
        int col = n0 + wc2*64 + ni*16 + (lane & 15);
        #pragma unroll
        for (int j = 0; j < 4; ++j) {
          int rr = lrow + j;
          if (rr < R && col < Vc) {
            int val = meta[1 + rr];
            int t = val >> 7, b = val & 127;
            outf[(size_t)b*(TMAXc*Vc) + (size_t)t*Vc + col] = acc[mi][ni][j] + bfc[col];
          }
        }
      }
  }
#undef STAGE_FC
}

// ---------------- launch ----------------

extern "C" void kernel_launch(void* const* d_in, const int* in_sizes, int n_in,
                              void* d_out, int out_size, void* d_ws, size_t ws_size,
                              hipStream_t stream)
{
  const float* enc   = (const float*)d_in[0];
  const int*   gt    = (const int*)  d_in[1];
  const int*   lens  = (const int*)  d_in[2];
  const float* emb   = (const float*)d_in[3];
  const float* Winit = (const float*)d_in[4];
  const float* binit = (const float*)d_in[5];
  const float* gam   = (const float*)d_in[6];
  const float* bet   = (const float*)d_in[7];
  const float* Wih   = (const float*)d_in[8];
  const float* bih   = (const float*)d_in[9];
  const float* Whh   = (const float*)d_in[10];
  const float* bhh   = (const float*)d_in[11];
  const float* Wfc   = (const float*)d_in[12];
  const float* bfc   = (const float*)d_in[13];
  float* out = (float*)d_out;

  char* ws = (char*)d_ws;
  size_t off = 0;
  auto alloc = [&](size_t bytes) -> char* {
    char* p = ws + off;
    off += (bytes + 255) & ~(size_t)255;
    return p;
  };

  bf16* featB  = (bf16*)alloc((size_t)Bc*Fc*2);
  bf16* WinitB = (bf16*)alloc((size_t)Ec*Fc*2);
  bf16* WihpB  = (bf16*)alloc((size_t)G4c*Ec*2);
  bf16* WhhHi  = (bf16*)alloc((size_t)G4c*Hc*2);
  bf16* WhhLo  = (bf16*)alloc((size_t)G4c*Hc*2);
  bf16* WfcHi  = (bf16*)alloc((size_t)Vc*Hc*2);
  bf16* WfcLo  = (bf16*)alloc((size_t)Vc*Hc*2);
  float* bcomb = (float*)alloc((size_t)G4c*4);
  bf16* Xall   = (bf16*)alloc((size_t)MALLc*Ec*2);
  bf16* Xg     = (bf16*)alloc((size_t)MALLc*G4c*2);
  bf16* hChH   = (bf16*)alloc((size_t)(NSTEP+1)*Bc*Hc*2);
  bf16* hChL   = (bf16*)alloc((size_t)(NSTEP+1)*Bc*Hc*2);
  bf16* HallH  = (bf16*)alloc((size_t)MOUTc*Hc*2);
  bf16* HallL  = (bf16*)alloc((size_t)MOUTc*Hc*2);
  float* part  = (float*)alloc((size_t)8*128*512*4);
  int*  meta   = (int*) alloc((size_t)(1 + MOUTc)*4);
  int*  flg    = (int*) alloc((size_t)384*4);

  if (off > ws_size) return;

  hipMemsetAsync(hChH, 0, (size_t)Bc*Hc*2, stream);
  hipMemsetAsync(hChL, 0, (size_t)Bc*Hc*2, stream);
  hipMemsetAsync(flg, 0, (size_t)384*4, stream);

  mean_kernel<<<256, 256, 0, stream>>>(enc, featB);
  conv_kernel<<<(Ec*Fc/4 + 255)/256, 256, 0, stream>>>(Winit, WinitB, Ec*Fc/4);
  permconv_ih<<<(G4c*Ec/4 + 255)/256, 256, 0, stream>>>(Wih, WihpB);
  permsplit_hh<<<(G4c*Hc/4 + 255)/256, 256, 0, stream>>>(Whh, WhhHi, WhhLo);
  split_kernel<<<(Vc*Hc/4 + 255)/256, 256, 0, stream>>>(Wfc, WfcHi, WfcLo, Vc*Hc/4);
  bcomb_kernel<<<(G4c + 255)/256, 256, 0, stream>>>(bih, bhh, bcomb);
  gather_kernel<<<(MOUTc*(Ec/4) + 255)/256, 256, 0, stream>>>(emb, gt, Xall);
  build_ridx<<<(MOUTc + 255)/256, 256, 0, stream>>>(lens, meta);
  zerofill<<<(MOUTc*2500 + 255)/256, 256, 0, stream>>>(lens, out);

  initA<<<32, 256, 0, stream>>>(featB, WinitB, part);
  initB<<<(128*512 + 255)/256, 256, 0, stream>>>(part, binit, gam, bet, Xall);

  gemm_xg<<<31*32, 256, 0, stream>>>(
      Xall, WihpB, MALLc, G4c, Ec, 31, bcomb, Xg);

  hipFuncSetAttribute(reinterpret_cast<const void*>(lstm_persist),
                      hipFuncAttributeMaxDynamicSharedMemorySize, 133120);
  lstm_persist<<<NBLK, 256, 133120, stream>>>(
      WhhHi, WhhLo, Xg, hChH, hChL, HallH, HallL,
      WfcHi, WfcLo, bfc, lens, meta, out, flg);
}

// Round 17
// 601.853 us; speedup vs baseline: 1.0849x; 1.0295x over previous
//
#include <hip/hip_runtime.h>
#include <math.h>

typedef __bf16 bf16;
typedef __bf16 bf16x8 __attribute__((ext_vector_type(8)));
typedef __bf16 bf16x4 __attribute__((ext_vector_type(4)));
typedef float f32x4 __attribute__((ext_vector_type(4)));

#define MFMA_B16(a,b,c) __builtin_amdgcn_mfma_f32_16x16x32_bf16((a),(b),(c),0,0,0)

constexpr int TMAXc = 30;
constexpr int Bc = 128, Pc = 196, Fc = 2048, Ec = 512, Hc = 1024, Vc = 10000;
constexpr int G4c = 4 * Hc;          // 4096
constexpr int NSTEP = TMAXc + 1;     // 31
constexpr int MALLc = NSTEP * Bc;    // 3968
constexpr int MOUTc = TMAXc * Bc;    // 3840
constexpr int NBLK = 256;            // persistent kernel grid

__device__ __forceinline__ float fsigm(float x){
  return __fdividef(1.0f, 1.0f + __expf(-x));
}
__device__ __forceinline__ float ftanh(float x){
  return 1.0f - __fdividef(2.0f, __expf(2.0f*x) + 1.0f);
}
// 4-way select by runtime index (3 cndmask, no scratch - rule #20 safe)
__device__ __forceinline__ float sel4(float a, float b, float c, float d, int i){
  float x = (i & 1) ? b : a;
  float y = (i & 1) ? d : c;
  return (i & 2) ? y : x;
}

__device__ __forceinline__ void gll16(const void* g, void* l){
  __builtin_amdgcn_global_load_lds((const __attribute__((address_space(1))) void*)g,
                                   (__attribute__((address_space(3))) void*)l, 16, 0, 0);
}

// 16B write-through store (bypasses L1/L2, lands at coherence point / MALL)
__device__ __forceinline__ void wt16(bf16* p, bf16x8 v){
  asm volatile("global_store_dwordx4 %0, %1, off sc0 sc1" :: "v"(p), "v"(v) : "memory");
}

__device__ __forceinline__ int aldf(int* f){
  return __hip_atomic_load(f, __ATOMIC_RELAXED, __HIP_MEMORY_SCOPE_AGENT);
}

// bounded spin: escapes after ~1ms (s_memrealtime = 100 MHz const clock)
__device__ __forceinline__ void waitflag(int* f, int tgt){
  long long t0 = __builtin_amdgcn_s_memrealtime();
  while (aldf(f) < tgt) {
    __builtin_amdgcn_s_sleep(1);
    if (__builtin_amdgcn_s_memrealtime() - t0 > 100000) break;
  }
}

// poll gate0 while snapshotting gates 1-3 in the same round trip
__device__ __forceinline__ void waitflags4(int* F, int& f1, int& f2, int& f3){
  long long t0 = __builtin_amdgcn_s_memrealtime();
  for (;;) {
    int f0 = aldf(F + 0);
    f1 = aldf(F + 1);
    f2 = aldf(F + 2);
    f3 = aldf(F + 3);
    if (f0 >= 32) break;
    __builtin_amdgcn_s_sleep(1);
    if (__builtin_amdgcn_s_memrealtime() - t0 > 100000) break;
  }
}

// ---------------- prep kernels ----------------

__global__ void mean_kernel(const float* __restrict__ enc, bf16* __restrict__ feat){
  int blk = blockIdx.x, b = blk >> 1, half = blk & 1;
  int f0 = half*1024 + threadIdx.x*4;
  const float* p = enc + (size_t)b*Pc*Fc + f0;
  float4 s = {0.f,0.f,0.f,0.f};
  #pragma unroll 4
  for (int q = 0; q < Pc; ++q) {
    float4 v = *(const float4*)(p + (size_t)q*Fc);
    s.x += v.x; s.y += v.y; s.z += v.z; s.w += v.w;
  }
  const float r = 1.0f/(float)Pc;
  bf16x4 o = { (bf16)(s.x*r), (bf16)(s.y*r), (bf16)(s.z*r), (bf16)(s.w*r) };
  *(bf16x4*)&feat[b*Fc + f0] = o;
}

// all elementwise prep fused into one launch; exact block-range partition
__global__ void prep_all(
  const float* __restrict__ Winit, bf16* __restrict__ WinitB,
  const float* __restrict__ Wih,   bf16* __restrict__ WihpB,
  const float* __restrict__ Whh,   bf16* __restrict__ WhhHi, bf16* __restrict__ WhhLo,
  const float* __restrict__ Wfc,   bf16* __restrict__ WfcHi, bf16* __restrict__ WfcLo,
  const float* __restrict__ bih,   const float* __restrict__ bhh, float* __restrict__ bcomb,
  const float* __restrict__ emb,   const int* __restrict__ gt, bf16* __restrict__ Xall,
  const int* __restrict__ lens,    int* __restrict__ meta, float* __restrict__ out)
{
  int blk = blockIdx.x, tid = threadIdx.x;
  if (blk < 1024) {                       // conv Winit -> bf16 (262144 x4)
    int i = blk*256 + tid;
    float4 v = ((const float4*)Winit)[i];
    bf16x4 o = { (bf16)v.x, (bf16)v.y, (bf16)v.z, (bf16)v.w };
    *(bf16x4*)&WinitB[i*4] = o;
  } else if (blk < 3072) {                // permconv_ih (524288 x4)
    int i4 = ((blk-1024)*256 + tid) * 4;
    int rp = i4 >> 9, k = i4 & 511;
    int g = rp & 3, j = rp >> 2;
    float4 v = *(const float4*)&Wih[(size_t)(g*Hc + j)*Ec + k];
    bf16x4 o = { (bf16)v.x, (bf16)v.y, (bf16)v.z, (bf16)v.w };
    *(bf16x4*)&WihpB[i4] = o;
  } else if (blk < 7168) {                // permsplit_hh (1048576 x4)
    int i4 = ((blk-3072)*256 + tid) * 4;
    int rp = i4 >> 10, k = i4 & 1023;
    int g = rp & 3, j = rp >> 2;
    float4 v = *(const float4*)&Whh[(size_t)(g*Hc + j)*Hc + k];
    bf16 h0=(bf16)v.x, h1=(bf16)v.y, h2=(bf16)v.z, h3=(bf16)v.w;
    bf16x4 hi = { h0, h1, h2, h3 };
    bf16x4 lo = { (bf16)(v.x-(float)h0), (bf16)(v.y-(float)h1), (bf16)(v.z-(float)h2), (bf16)(v.w-(float)h3) };
    *(bf16x4*)&WhhHi[i4] = hi;
    *(bf16x4*)&WhhLo[i4] = lo;
  } else if (blk < 17168) {               // split Wfc (2560000 x4)
    int i = (blk-7168)*256 + tid;
    float4 v = ((const float4*)Wfc)[i];
    bf16 h0=(bf16)v.x, h1=(bf16)v.y, h2=(bf16)v.z, h3=(bf16)v.w;
    bf16x4 hi = { h0, h1, h2, h3 };
    bf16x4 lo = { (bf16)(v.x-(float)h0), (bf16)(v.y-(float)h1), (bf16)(v.z-(float)h2), (bf16)(v.w-(float)h3) };
    *(bf16x4*)&WfcHi[i*4] = hi;
    *(bf16x4*)&WfcLo[i*4] = lo;
  } else if (blk < 17184) {               // bcomb (4096)
    int i = (blk-17168)*256 + tid;
    int g = i & 3, j = i >> 2;
    bcomb[i] = bih[g*Hc + j] + bhh[g*Hc + j];
  } else if (blk < 19104) {               // gather (491520)
    int idx = (blk-17184)*256 + tid;
    int r = idx >> 7, ei = (idx & 127) * 4;
    int s = (r >> 7) + 1, b = r & 127;
    int tok = gt[b*(TMAXc+1) + (s-1)];
    float4 v = *(const float4*)(emb + (size_t)tok*Ec + ei);
    bf16x4 o = { (bf16)v.x, (bf16)v.y, (bf16)v.z, (bf16)v.w };
    *(bf16x4*)&Xall[(size_t)(s*Bc + b)*Ec + ei] = o;
  } else if (blk < 19119) {               // build_ridx (3840)
    int i = (blk-19104)*256 + tid;
    int t = i >> 7, b = i & 127;
    int S = 0, R = 0;
    for (int bb = 0; bb < 128; ++bb) {
      int l = lens[bb] - 1;
      S += (t < l) ? t : l;
      R += l;
    }
    if (i == 0) meta[0] = R;
    if (i >= R) meta[1 + i] = 0;
    if (t < lens[b] - 1) meta[1 + S + b] = i;
  } else {                                // zerofill (9600000)
    int i = (blk-19119)*256 + tid;
    int row = i / 2500, c4 = i - row*2500;
    int b = row / TMAXc, t = row - b*TMAXc;
    if (t >= lens[b] - 1) {
      float4 z = {0.f,0.f,0.f,0.f};
      *(float4*)(out + (size_t)row*Vc + c4*4) = z;
    }
  }
}

// ---------------- GEMM A split-K: x0 partials (32 blocks = 4 ntiles x 8 kchunks) ----------
__global__ __launch_bounds__(256, 2) void initA(
  const bf16* __restrict__ feat, const bf16* __restrict__ Wi, float* __restrict__ part)
{
  __shared__ alignas(16) bf16 sA[128*32], sB[128*32];
  int tid = threadIdx.x, lane = tid & 63, w = tid >> 6, wr = w >> 1, wc = w & 1;
  int nt = blockIdx.x & 3, kc = blockIdx.x >> 2;
  int n0 = nt*128;

  f32x4 acc[4][4] = {};
  for (int kt = kc*256; kt < kc*256 + 256; kt += 32) {
    #pragma unroll
    for (int is = 0; is < 2; ++is) {
      int p = tid*16 + is*4096;
      int r = p >> 6, c = (p & 63) >> 1;
      int ldsoff = w*512 + is*2048;
      gll16(feat + (size_t)r*Fc + kt + c, &sA[ldsoff]);
      gll16(Wi + (size_t)(n0 + r)*Fc + kt + c, &sB[ldsoff]);
    }
    __syncthreads();
    int koff = (lane >> 4) * 8;
    bf16x8 ah[4], bh[4];
    #pragma unroll
    for (int mi = 0; mi < 4; ++mi)
      ah[mi] = *(const bf16x8*)&sA[(wr*64 + mi*16 + (lane & 15))*32 + koff];
    #pragma unroll
    for (int ni = 0; ni < 4; ++ni)
      bh[ni] = *(const bf16x8*)&sB[(wc*64 + ni*16 + (lane & 15))*32 + koff];
    #pragma unroll
    for (int mi = 0; mi < 4; ++mi)
      #pragma unroll
      for (int ni = 0; ni < 4; ++ni)
        acc[mi][ni] = MFMA_B16(ah[mi], bh[ni], acc[mi][ni]);
    __syncthreads();
  }
  #pragma unroll
  for (int mi = 0; mi < 4; ++mi)
    #pragma unroll
    for (int ni = 0; ni < 4; ++ni) {
      int lrow = wr*64 + mi*16 + ((lane >> 4) << 2);
      int col = n0 + wc*64 + ni*16 + (lane & 15);
      #pragma unroll
      for (int j = 0; j < 4; ++j)
        part[((size_t)kc*128 + lrow + j)*512 + col] = acc[mi][ni][j];
    }
}

__global__ void initB(const float* __restrict__ part, const float* __restrict__ binit,
                      const float* __restrict__ gam, const float* __restrict__ bet,
                      bf16* __restrict__ Xall)
{
  int i = blockIdx.x*256 + threadIdx.x;
  if (i >= 128*512) return;
  int col = i & 511;
  float v = 0.f;
  #pragma unroll
  for (int kc = 0; kc < 8; ++kc) v += part[(size_t)kc*128*512 + i];
  const float rbn = rsqrtf(1.0f + 1e-5f);
  v = fsigm(v + binit[col]);
  v = gam[col]*(v*rbn) + bet[col];
  Xall[i] = (bf16)v;
}

// ---------------- Xg GEMM (128x128 tile, BK=32, nt-major, XCD swizzle) --------
__global__ __launch_bounds__(256, 2) void gemm_xg(
  const bf16* __restrict__ A, const bf16* __restrict__ B,
  int M, int N, int K, int mtiles,
  const float* __restrict__ p0, bf16* __restrict__ outb)
{
  constexpr int BK = 32;
  __shared__ alignas(16) bf16 sAh[128*BK], sBh[128*BK];

  int tid = threadIdx.x;
  int lane = tid & 63, w = tid >> 6, wr = w >> 1, wc = w & 1;
  int bid = blockIdx.x;
  {
    int nwg = gridDim.x, q = nwg >> 3, r = nwg & 7;
    int x = bid & 7, o = bid >> 3;
    bid = (x < r ? x*(q+1) : r*(q+1) + (x-r)*q) + o;
  }
  int nt = bid / mtiles, mt = bid - nt*mtiles;
  int m0 = mt*128, n0 = nt*128;

  int sr = (tid*16) >> 6;
  int gr0 = m0 + sr, gr1 = m0 + sr + 64;

  f32x4 acc[4][4] = {};

  for (int kt = 0; kt < K; kt += BK) {
    #pragma unroll
    for (int is = 0; is < 2; ++is) {
      int p = tid*16 + is*4096;
      int c = (p & 63) >> 1;
      int r = p >> 6;
      int ldsoff = w*512 + is*2048;
      int ga = is ? gr1 : gr0;
      gll16(A + (size_t)ga*K + kt + c, &sAh[ldsoff]);
      gll16(B + (size_t)(n0 + r)*K + kt + c, &sBh[ldsoff]);
    }
    __syncthreads();

    int koff = (lane >> 4) * 8;
    bf16x8 ah[4], bh[4];
    #pragma unroll
    for (int mi = 0; mi < 4; ++mi)
      ah[mi] = *(const bf16x8*)&sAh[(wr*64 + mi*16 + (lane & 15))*BK + koff];
    #pragma unroll
    for (int ni = 0; ni < 4; ++ni)
      bh[ni] = *(const bf16x8*)&sBh[(wc*64 + ni*16 + (lane & 15))*BK + koff];
    #pragma unroll
    for (int mi = 0; mi < 4; ++mi)
      #pragma unroll
      for (int ni = 0; ni < 4; ++ni)
        acc[mi][ni] = MFMA_B16(ah[mi], bh[ni], acc[mi][ni]);
    __syncthreads();
  }

  #pragma unroll
  for (int mi = 0; mi < 4; ++mi)
    #pragma unroll
    for (int ni = 0; ni < 4; ++ni) {
      int lrow = m0 + wr*64 + mi*16 + ((lane >> 4) << 2);
      int col = n0 + wc*64 + ni*16 + (lane & 15);
      #pragma unroll
      for (int j = 0; j < 4; ++j)
        outb[(size_t)(lrow + j)*G4c + col] = (bf16)(acc[mi][ni][j] + p0[col]);
    }
}

// ---------------- fused persistent LSTM recurrence + FC GEMM (R15 structure) ----------
__global__ __launch_bounds__(256, 1) void lstm_persist(
  const bf16* __restrict__ Whi, const bf16* __restrict__ Wlo,
  const bf16* __restrict__ Xg,
  bf16* __restrict__ hCh, bf16* __restrict__ hCl,
  bf16* __restrict__ Hh, bf16* __restrict__ Hl,
  const bf16* __restrict__ WfcHi, const bf16* __restrict__ WfcLo,
  const float* __restrict__ bfc,
  const int* __restrict__ lens, const int* __restrict__ meta,
  float* __restrict__ outf,
  int* __restrict__ flg)      // [0,256) chain flags; [256,316) hallflg; [320] tilectr
{
  extern __shared__ char sWc[];
  int tid = threadIdx.x, lane = tid & 63, w = tid >> 6;
  int bid = blockIdx.x;
  int strip = bid >> 1, rh = bid & 1;
  int pc0 = strip * 32;
  int row0 = rh * 64 + w * 16;
  int grp = strip >> 5;
  char* scr = sWc + 131072 + w*512;   // per-wave: hi [16][8] @0, lo @256
  int* hallflg = flg + 256;
  int* tilectr = flg + 320;

  // ---- fill W slice into LDS: chunk (ks,ni) holds lanes' fragments linearly ----
  for (int ch = tid; ch < 4096; ch += 256) {
    int p = ch >> 7;
    int k = (ch & 127) * 8;
    int ni = p >> 4, bp = p & 15;
    int ks = k >> 5, kg = (k >> 3) & 3;
    int off = (((ks*2 + ni)*4 + kg)*16 + bp) * 16;
    bf16x8 vh = *(const bf16x8*)&Whi[(size_t)(pc0 + p)*Hc + k];
    bf16x8 vl = *(const bf16x8*)&Wlo[(size_t)(pc0 + p)*Hc + k];
    *(bf16x8*)(sWc + off) = vh;
    *(bf16x8*)(sWc + 65536 + off) = vl;
  }
  __syncthreads();

  int bp = lane & 15;
  int bk = (lane >> 4) << 3;
  int rbase = row0 + ((lane >> 4) << 2);
  int e = lane & 3;
  const char* sWhiB = sWc + lane*16;
  const char* sWloB = sWc + 65536 + lane*16;

  int Lh = lens[rh * 64];
  if (Lh > NSTEP) Lh = NSTEP;
  int lenv = lens[row0 + (lane & 15)] - 1;

  float creg[2] = {0.f, 0.f};
  float xgv[2][4];
  #pragma unroll
  for (int ni = 0; ni < 2; ++ni)
    #pragma unroll
    for (int j = 0; j < 4; ++j)
      xgv[ni][j] = (float)Xg[(size_t)(rbase + j)*G4c + pc0 + ni*16 + bp];

#define GATEQ(g, fg) do { if (s > 0) { \
    if (tid == 0 && (fg) < 32) waitflag(&flg[(s*2 + rh)*4 + (g)], 32); \
    __builtin_amdgcn_s_barrier(); \
    asm volatile("" ::: "memory"); } } while (0)

#define LOADQ(qh, ql, g) do { \
    _Pragma("unroll") \
    for (int i = 0; i < 8; ++i) { \
      qh[i] = *(const bf16x8*)(pah + ((g)*8 + i)*32); \
      ql[i] = *(const bf16x8*)(pal + ((g)*8 + i)*32); \
    } \
    asm volatile("" ::: "memory"); } while (0)

#define MFMAQ(qh, ql, g) do { \
    _Pragma("unroll") \
    for (int i = 0; i < 8; ++i) { \
      int ks = (g)*8 + i; \
      _Pragma("unroll") \
      for (int ni = 0; ni < 2; ++ni) { \
        bf16x8 bvh = *(const bf16x8*)(sWhiB + (ks*2 + ni)*1024); \
        bf16x8 bvl = *(const bf16x8*)(sWloB + (ks*2 + ni)*1024); \
        aHH[ni] = MFMA_B16(qh[i], bvh, aHH[ni]); \
        aHL[ni] = MFMA_B16(qh[i], bvl, aHL[ni]); \
        aLH[ni] = MFMA_B16(ql[i], bvh, aLH[ni]); \
      } \
    } } while (0)

  #pragma unroll 1
  for (int s = 0; s < Lh; ++s) {
    const bf16* pah = hCh + (size_t)s*Bc*Hc + (size_t)(row0 + bp)*Hc + bk;
    const bf16* pal = hCl + (size_t)s*Bc*Hc + (size_t)(row0 + bp)*Hc + bk;
    bf16* hwh = hCh + (size_t)(s+1)*Bc*Hc;
    bf16* hwl = hCl + (size_t)(s+1)*Bc*Hc;

    f32x4 aHH[2], aHL[2], aLH[2];
    #pragma unroll
    for (int ni = 0; ni < 2; ++ni) {
      #pragma unroll
      for (int j = 0; j < 4; ++j) aHH[ni][j] = xgv[ni][j];
      aHL[ni] = (f32x4){0.f,0.f,0.f,0.f};
      aLH[ni] = (f32x4){0.f,0.f,0.f,0.f};
    }

    bf16x8 qh0[8], ql0[8], qh1[8], ql1[8];
    int f1 = 32, f2 = 32, f3 = 32;

    if (s > 0) {
      if (tid == 0) waitflags4(&flg[(s*2 + rh)*4], f1, f2, f3);
      __builtin_amdgcn_s_barrier();
      asm volatile("" ::: "memory");
    }
    LOADQ(qh0, ql0, 0);
    GATEQ(1, f1); LOADQ(qh1, ql1, 1);
    MFMAQ(qh0, ql0, 0);
    GATEQ(2, f2); LOADQ(qh0, ql0, 2);
    MFMAQ(qh1, ql1, 1);
    GATEQ(3, f3); LOADQ(qh1, ql1, 3);
    MFMAQ(qh0, ql0, 2);
    MFMAQ(qh1, ql1, 3);

    // ---- lane-specialized LSTM epilogue: lane e owns row rbase+e ----
    #pragma unroll
    for (int ni = 0; ni < 2; ++ni) {
      float v0 = aHH[ni][0] + aHL[ni][0] + aLH[ni][0];
      float v1 = aHH[ni][1] + aHL[ni][1] + aLH[ni][1];
      float v2 = aHH[ni][2] + aHL[ni][2] + aLH[ni][2];
      float v3 = aHH[ni][3] + aHL[ni][3] + aLH[ni][3];
      float g0 = sel4(v0, v1, v2, v3, e);
      float g1 = __shfl_xor(sel4(v0, v1, v2, v3, e ^ 1), 1);
      float g2 = __shfl_xor(sel4(v0, v1, v2, v3, e ^ 2), 2);
      float g3 = __shfl_xor(sel4(v0, v1, v2, v3, e ^ 3), 3);
      float gI = sel4(g0, g1, g2, g3, e);
      float gF = sel4(g0, g1, g2, g3, e ^ 1);
      float gG = sel4(g0, g1, g2, g3, e ^ 2);
      float gO = sel4(g0, g1, g2, g3, e ^ 3);

      float co = creg[ni];
      float cn = fsigm(gF)*co + fsigm(gI)*ftanh(gG);
      float hn = fsigm(gO)*ftanh(cn);
      creg[ni] = cn;
      bf16 hhi = (bf16)hn;
      int r16 = ((lane >> 4) << 2) + e;
      int c8  = ni*4 + (bp >> 2);
      *(bf16*)(scr + (r16*8 + c8)*2) = hhi;
      *(bf16*)(scr + 256 + (r16*8 + c8)*2) = (bf16)(hn - (float)hhi);
    }

    asm volatile("s_waitcnt lgkmcnt(0)" ::: "memory");
    __builtin_amdgcn_sched_barrier(0);

    // lanes 0-31: coalesced 16B write-through chain stores
    if (lane < 32) {
      int r = lane & 15, buf = lane >> 4;
      bf16x8 vv = *(const bf16x8*)(scr + buf*256 + r*16);
      bf16* dst = (buf ? hwl : hwh) + (size_t)(row0 + r)*Hc + strip*8;
      wt16(dst, vv);
    }

    __syncthreads();   // drains this step's chain stores AND prev step's Hall stores
    if (tid == 0) {
      if (s + 1 < Lh)
        __hip_atomic_fetch_add(&flg[((s+1)*2 + rh)*4 + grp], 1,
                               __ATOMIC_RELAXED, __HIP_MEMORY_SCOPE_AGENT);
      if (s >= 2)
        __hip_atomic_fetch_add(&hallflg[(s-2)*2 + rh], 1,
                               __ATOMIC_RELAXED, __HIP_MEMORY_SCOPE_AGENT);
    }

    // ---- off-path: Hall WT stores (lanes 32-63, masked) + Xg prefetch ----
    if (s > 0 && lane >= 32 && (s - 1) < lenv) {
      int r = lane & 15, buf = (lane >> 4) & 1;
      bf16x8 vv = *(const bf16x8*)(scr + buf*256 + r*16);
      wt16((buf ? Hl : Hh) + (size_t)((s-1)*Bc + row0 + r)*Hc + strip*8, vv);
    }
    if (s + 1 < Lh) {
      #pragma unroll
      for (int ni = 0; ni < 2; ++ni)
        #pragma unroll
        for (int j = 0; j < 4; ++j)
          xgv[ni][j] = (float)Xg[(size_t)((s+1)*Bc + rbase + j)*G4c + pc0 + ni*16 + bp];
    }
  }
#undef GATEQ
#undef LOADQ
#undef MFMAQ

  __syncthreads();   // drains final Hall stores (t = Lh-2)
  if (tid == 0) {
    if (Lh >= 2)
      __hip_atomic_fetch_add(&hallflg[(Lh-2)*2 + rh], 1,
                             __ATOMIC_RELAXED, __HIP_MEMORY_SCOPE_AGENT);
    for (int t = Lh - 1; t < TMAXc; ++t)
      __hip_atomic_fetch_add(&hallflg[t*2 + rh], 1,
                             __ATOMIC_RELAXED, __HIP_MEMORY_SCOPE_AGENT);
  }

  // ================= FC mode (4-buffer counted-vmcnt pipeline) =================
  bf16* L = (bf16*)sWc;   // buf b (0..3) @ b*16384 elems: Ahi@0 Bhi@4096 Alo@8192 Blo@12288
  int* ctrl = (int*)(sWc + 131072 + 2044);

  int R = meta[0];
  int mtilesFC = (R + 127) >> 7;
  int ntFC = mtilesFC * 79;
  int wr = w >> 1, wc2 = w & 1;

#define STAGE_FC(bufb, kt) do { \
    _Pragma("unroll") \
    for (int is = 0; is < 2; ++is) { \
      int p = tid*16 + is*4096; \
      int c = (p & 63) >> 1; \
      int r = p >> 6; \
      int eo = (bufb)*16384 + w*512 + is*2048; \
      int ga = is ? gr1 : gr0; \
      int rb = n0 + r; if (rb > 9999) rb = 9999; \
      gll16(Hh + (size_t)ga*Hc + (kt) + c, L + eo); \
      gll16(WfcHi + (size_t)rb*Hc + (kt) + c, L + 4096 + eo); \
      gll16(Hl + (size_t)ga*Hc + (kt) + c, L + 8192 + eo); \
      gll16(WfcLo + (size_t)rb*Hc + (kt) + c, L + 12288 + eo); \
    } } while (0)

  #pragma unroll 1
  for (;;) {
    if (tid == 0) ctrl[0] = __hip_atomic_fetch_add(tilectr, 1,
                               __ATOMIC_RELAXED, __HIP_MEMORY_SCOPE_AGENT);
    __syncthreads();
    int idx = ctrl[0];
    __syncthreads();
    if (idx >= ntFC) break;
    int mt = idx / 79, ntc = idx - mt*79;
    int m0 = mt*128, n0 = ntc*128;
    int last = m0 + 127; if (last >= R) last = R - 1;
    int tmax = meta[1 + last] >> 7;
    if (tid == 0) {
      waitflag(&hallflg[tmax*2 + 0], 128);
      waitflag(&hallflg[tmax*2 + 1], 128);
    }
    __builtin_amdgcn_s_barrier();
    asm volatile("" ::: "memory");

    int sr = (tid*16) >> 6;
    int gr0 = meta[1 + m0 + sr], gr1 = meta[1 + m0 + sr + 64];

    f32x4 acc[4][4] = {};

    STAGE_FC(0, 0);
    STAGE_FC(1, 32);
    STAGE_FC(2, 64);

    #pragma unroll 1
    for (int ks = 0; ks < 32; ++ks) {
      if (ks <= 29)      asm volatile("s_waitcnt vmcnt(16)" ::: "memory");
      else if (ks == 30) asm volatile("s_waitcnt vmcnt(8)"  ::: "memory");
      else               asm volatile("s_waitcnt vmcnt(0)"  ::: "memory");
      __builtin_amdgcn_s_barrier();
      asm volatile("" ::: "memory");
      if (ks + 3 < 32) STAGE_FC((ks+3) & 3, (ks+3)*32);

      int koff = (lane >> 4) * 8;
      int bb = (ks & 3) * 16384;
      bf16x8 ah[4], bh[4], al[4], bl[4];
      #pragma unroll
      for (int mi = 0; mi < 4; ++mi) {
        int rr = wr*64 + mi*16 + (lane & 15);
        ah[mi] = *(const bf16x8*)&L[bb + rr*32 + koff];
        al[mi] = *(const bf16x8*)&L[bb + 8192 + rr*32 + koff];
      }
      #pragma unroll
      for (int ni = 0; ni < 4; ++ni) {
        int rr = wc2*64 + ni*16 + (lane & 15);
        bh[ni] = *(const bf16x8*)&L[bb + 4096 + rr*32 + koff];
        bl[ni] = *(const bf16x8*)&L[bb + 12288 + rr*32 + koff];
      }
      #pragma unroll
      for (int mi = 0; mi < 4; ++mi)
        #pragma unroll
        for (int ni = 0; ni < 4; ++ni) {
          acc[mi][ni] = MFMA_B16(ah[mi], bh[ni], acc[mi][ni]);
          acc[mi][ni] = MFMA_B16(ah[mi], bl[ni], acc[mi][ni]);
          acc[mi][ni] = MFMA_B16(al[mi], bh[ni], acc[mi][ni]);
        }
    }

    // epilogue: scatter to out via meta
    #pragma unroll
    for (int mi = 0; mi < 4; ++mi)
      #pragma unroll
      for (int ni = 0; ni < 4; ++ni) {
        int lrow = m0 + wr*64 + mi*16 + ((lane >> 4) << 2);
        int col = n0 + wc2*64 + ni*16 + (lane & 15);
        #pragma unroll
        for (int j = 0; j < 4; ++j) {
          int rr = lrow + j;
          if (rr < R && col < Vc) {
            int val = meta[1 + rr];
            int t = val >> 7, b = val & 127;
            outf[(size_t)b*(TMAXc*Vc) + (size_t)t*Vc + col] = acc[mi][ni][j] + bfc[col];
          }
        }
      }
  }
#undef STAGE_FC
}

// ---------------- launch ----------------

extern "C" void kernel_launch(void* const* d_in, const int* in_sizes, int n_in,
                              void* d_out, int out_size, void* d_ws, size_t ws_size,
                              hipStream_t stream)
{
  const float* enc   = (const float*)d_in[0];
  const int*   gt    = (const int*)  d_in[1];
  const int*   lens  = (const int*)  d_in[2];
  const float* emb   = (const float*)d_in[3];
  const float* Winit = (const float*)d_in[4];
  const float* binit = (const float*)d_in[5];
  const float* gam   = (const float*)d_in[6];
  const float* bet   = (const float*)d_in[7];
  const float* Wih   = (const float*)d_in[8];
  const float* bih   = (const float*)d_in[9];
  const float* Whh   = (const float*)d_in[10];
  const float* bhh   = (const float*)d_in[11];
  const float* Wfc   = (const float*)d_in[12];
  const float* bfc   = (const float*)d_in[13];
  float* out = (float*)d_out;

  char* ws = (char*)d_ws;
  size_t off = 0;
  auto alloc = [&](size_t bytes) -> char* {
    char* p = ws + off;
    off += (bytes + 255) & ~(size_t)255;
    return p;
  };

  bf16* featB  = (bf16*)alloc((size_t)Bc*Fc*2);
  bf16* WinitB = (bf16*)alloc((size_t)Ec*Fc*2);
  bf16* WihpB  = (bf16*)alloc((size_t)G4c*Ec*2);
  bf16* WhhHi  = (bf16*)alloc((size_t)G4c*Hc*2);
  bf16* WhhLo  = (bf16*)alloc((size_t)G4c*Hc*2);
  bf16* WfcHi  = (bf16*)alloc((size_t)Vc*Hc*2);
  bf16* WfcLo  = (bf16*)alloc((size_t)Vc*Hc*2);
  float* bcomb = (float*)alloc((size_t)G4c*4);
  bf16* Xall   = (bf16*)alloc((size_t)MALLc*Ec*2);
  bf16* Xg     = (bf16*)alloc((size_t)MALLc*G4c*2);
  bf16* hChH   = (bf16*)alloc((size_t)(NSTEP+1)*Bc*Hc*2);
  bf16* hChL   = (bf16*)alloc((size_t)(NSTEP+1)*Bc*Hc*2);
  bf16* HallH  = (bf16*)alloc((size_t)MOUTc*Hc*2);
  bf16* HallL  = (bf16*)alloc((size_t)MOUTc*Hc*2);
  float* part  = (float*)alloc((size_t)8*128*512*4);
  int*  meta   = (int*) alloc((size_t)(1 + MOUTc)*4);
  int*  flg    = (int*) alloc((size_t)384*4);

  if (off > ws_size) return;

  hipMemsetAsync(hChH, 0, (size_t)Bc*Hc*2, stream);
  hipMemsetAsync(hChL, 0, (size_t)Bc*Hc*2, stream);
  hipMemsetAsync(flg, 0, (size_t)384*4, stream);

  mean_kernel<<<256, 256, 0, stream>>>(enc, featB);
  prep_all<<<56619, 256, 0, stream>>>(
      Winit, WinitB, Wih, WihpB, Whh, WhhHi, WhhLo,
      Wfc, WfcHi, WfcLo, bih, bhh, bcomb,
      emb, gt, Xall, lens, meta, out);

  initA<<<32, 256, 0, stream>>>(featB, WinitB, part);
  initB<<<(128*512 + 255)/256, 256, 0, stream>>>(part, binit, gam, bet, Xall);

  gemm_xg<<<31*32, 256, 0, stream>>>(
      Xall, WihpB, MALLc, G4c, Ec, 31, bcomb, Xg);

  hipFuncSetAttribute(reinterpret_cast<const void*>(lstm_persist),
                      hipFuncAttributeMaxDynamicSharedMemorySize, 133120);
  lstm_persist<<<NBLK, 256, 133120, stream>>>(
      WhhHi, WhhLo, Xg, hChH, hChL, HallH, HallL,
      WfcHi, WfcLo, bfc, lens, meta, out, flg);
}